// Round 1
// baseline (1599.091 us; speedup 1.0000x reference)
//
#include <hip/hip_runtime.h>

#define N_NODES 10000
#define N_EDGES 160000
#define DIM 512
#define HDIM 256
#define EDIM 16
#define BN_EPS 1e-5f

// ---------------- helpers ----------------
__device__ __forceinline__ float sigmoid_f(float x) {
    return 1.0f / (1.0f + __expf(-x));
}
__device__ __forceinline__ float softplus_f(float x) {
    // logaddexp(x,0) = max(x,0) + log1p(exp(-|x|))
    return fmaxf(x, 0.0f) + __logf(1.0f + __expf(-fabsf(x)));
}

// ---------------- CSR build ----------------
__global__ void k_hist(const int* __restrict__ dst, int* __restrict__ cnt) {
    int e = blockIdx.x * blockDim.x + threadIdx.x;
    if (e < N_EDGES) atomicAdd(&cnt[dst[e]], 1);
}

// in-place: offs[] holds counts on entry, exclusive prefix on exit; also writes dinv
__global__ __launch_bounds__(1024) void k_scan(int* __restrict__ offs, float* __restrict__ dinv) {
    __shared__ int sbuf[1024];
    __shared__ int carry;
    if (threadIdx.x == 0) carry = 0;
    __syncthreads();
    for (int base = 0; base < N_NODES; base += 1024) {
        int idx = base + threadIdx.x;
        int v = (idx < N_NODES) ? offs[idx] : 0;
        if (idx < N_NODES) dinv[idx] = rsqrtf((float)v + 1.0f);  // deg incl self-loop
        sbuf[threadIdx.x] = v;
        __syncthreads();
        for (int off = 1; off < 1024; off <<= 1) {
            int t = (threadIdx.x >= off) ? sbuf[threadIdx.x - off] : 0;
            __syncthreads();
            sbuf[threadIdx.x] += t;
            __syncthreads();
        }
        if (idx < N_NODES) offs[idx] = carry + sbuf[threadIdx.x] - v;
        __syncthreads();
        if (threadIdx.x == 1023) carry += sbuf[1023];
        __syncthreads();
    }
    if (threadIdx.x == 0) offs[N_NODES] = carry;
}

__global__ void k_scatter(const int* __restrict__ dst, const int* __restrict__ offs,
                          int* __restrict__ cursor, int* __restrict__ eid) {
    int e = blockIdx.x * blockDim.x + threadIdx.x;
    if (e < N_EDGES) {
        int d = dst[e];
        int p = offs[d] + atomicAdd(&cursor[d], 1);
        eid[p] = e;
    }
}

// ---------------- fp32 tiled GEMM: C[M x ncols] = A[M x K] @ W[K x ncols] (+bias)(relu) ----------------
#define BM 64
#define BNT 64
#define BK 16
__global__ __launch_bounds__(256) void k_gemm(
    const float* __restrict__ A, int M, int K,
    const float* __restrict__ W, int ldw,
    const float* __restrict__ bias,
    float* __restrict__ C, int ncols, int do_relu)
{
    __shared__ __align__(16) float As[BK][BM];   // transposed A tile: As[k][m]
    __shared__ __align__(16) float Bs[BK][BNT];  // Bs[k][n]
    int tid = threadIdx.x;
    int tx = tid & 15, ty = tid >> 4;
    int row0 = blockIdx.x * BM;
    int col0 = blockIdx.y * BNT;
    float acc[4][4] = {};
    int ar  = tid >> 2;          // A tile row 0..63
    int akq = (tid & 3) << 2;    // A tile k quad
    int wc  = tid & 63;          // W tile col
    int wk  = tid >> 6;          // W tile k base
    for (int k0 = 0; k0 < K; k0 += BK) {
        float4 av4 = make_float4(0.f, 0.f, 0.f, 0.f);
        int gr = row0 + ar;
        if (gr < M) av4 = *(const float4*)(A + (size_t)gr * K + k0 + akq);
        As[akq + 0][ar] = av4.x;
        As[akq + 1][ar] = av4.y;
        As[akq + 2][ar] = av4.z;
        As[akq + 3][ar] = av4.w;
#pragma unroll
        for (int i = 0; i < 4; i++)
            Bs[wk + 4 * i][wc] = W[(size_t)(k0 + wk + 4 * i) * ldw + col0 + wc];
        __syncthreads();
#pragma unroll
        for (int k = 0; k < BK; k++) {
            float4 a = *(const float4*)&As[k][ty * 4];
            float4 b = *(const float4*)&Bs[k][tx * 4];
            acc[0][0] += a.x * b.x; acc[0][1] += a.x * b.y; acc[0][2] += a.x * b.z; acc[0][3] += a.x * b.w;
            acc[1][0] += a.y * b.x; acc[1][1] += a.y * b.y; acc[1][2] += a.y * b.z; acc[1][3] += a.y * b.w;
            acc[2][0] += a.z * b.x; acc[2][1] += a.z * b.y; acc[2][2] += a.z * b.z; acc[2][3] += a.z * b.w;
            acc[3][0] += a.w * b.x; acc[3][1] += a.w * b.y; acc[3][2] += a.w * b.z; acc[3][3] += a.w * b.w;
        }
        __syncthreads();
    }
#pragma unroll
    for (int i = 0; i < 4; i++) {
        int row = row0 + ty * 4 + i;
        if (row >= M) continue;
#pragma unroll
        for (int j = 0; j < 4; j++) {
            int col = col0 + tx * 4 + j;
            float v = acc[i][j];
            if (bias) v += bias[col];
            if (do_relu) v = fmaxf(v, 0.f);
            C[(size_t)row * ncols + col] = v;
        }
    }
}

// ---------------- CGConv edge aggregation + BN + residual + ReLU ----------------
// block = node i, 256 threads, 2 channels/thread.
// gate_f = Pf[i] + Qf[src] + ea@WfE (+bf already folded into Pf)
__global__ __launch_bounds__(256) void k_cg_aggr(
    const float* __restrict__ xin,
    const float* __restrict__ Pf, const float* __restrict__ Qf,
    const float* __restrict__ Ps, const float* __restrict__ Qs,
    const float* __restrict__ WfE, const float* __restrict__ WsE,  // [16][512] each
    const float* __restrict__ gamma, const float* __restrict__ beta,
    const float* __restrict__ mean, const float* __restrict__ var,
    const int* __restrict__ offs, const int* __restrict__ eid,
    const int* __restrict__ srcv, const float* __restrict__ ea,
    float* __restrict__ xout)
{
    int i = blockIdx.x;
    int c0 = threadIdx.x;
    int c1 = threadIdx.x + 256;
    float wf0[EDIM], wf1[EDIM], ws0[EDIM], ws1[EDIM];
#pragma unroll
    for (int k = 0; k < EDIM; k++) {
        wf0[k] = WfE[k * DIM + c0];
        wf1[k] = WfE[k * DIM + c1];
        ws0[k] = WsE[k * DIM + c0];
        ws1[k] = WsE[k * DIM + c1];
    }
    size_t ib = (size_t)i * DIM;
    float pf0 = Pf[ib + c0], pf1 = Pf[ib + c1];
    float ps0 = Ps[ib + c0], ps1 = Ps[ib + c1];
    float acc0 = 0.f, acc1 = 0.f;
    int e0 = offs[i], e1 = offs[i + 1];
    __shared__ float sEa[8][EDIM];
    __shared__ int sSrc[8];
    for (int base = e0; base < e1; base += 8) {
        int g = min(8, e1 - base);
        __syncthreads();
        if (threadIdx.x < g * 16) {
            int j = threadIdx.x >> 4, k = threadIdx.x & 15;
            int e = eid[base + j];
            sEa[j][k] = ea[(size_t)e * EDIM + k];
            if (k == 0) sSrc[j] = srcv[e];
        }
        __syncthreads();
        for (int j = 0; j < g; j++) {
            int s = sSrc[j];
            const float* qf = Qf + (size_t)s * DIM;
            const float* qs = Qs + (size_t)s * DIM;
            float gf0 = pf0 + qf[c0], gf1 = pf1 + qf[c1];
            float gs0 = ps0 + qs[c0], gs1 = ps1 + qs[c1];
#pragma unroll
            for (int k = 0; k < EDIM; k++) {
                float a = sEa[j][k];
                gf0 += a * wf0[k]; gf1 += a * wf1[k];
                gs0 += a * ws0[k]; gs1 += a * ws1[k];
            }
            acc0 += sigmoid_f(gf0) * softplus_f(gs0);
            acc1 += sigmoid_f(gf1) * softplus_f(gs1);
        }
    }
    float bn0 = (acc0 - mean[c0]) * rsqrtf(var[c0] + BN_EPS) * gamma[c0] + beta[c0];
    float bn1 = (acc1 - mean[c1]) * rsqrtf(var[c1] + BN_EPS) * gamma[c1] + beta[c1];
    xout[ib + c0] = fmaxf(xin[ib + c0] + bn0, 0.f);
    xout[ib + c1] = fmaxf(xin[ib + c1] + bn1, 0.f);
}

// ---------------- GCN aggregation: relu(di*sum(dinv[s]*h[s]) + di^2*h[i] + b) ----------------
__global__ __launch_bounds__(256) void k_gcn_aggr(
    const float* __restrict__ h, const float* __restrict__ dinv,
    const float* __restrict__ bias,
    const int* __restrict__ offs, const int* __restrict__ eid,
    const int* __restrict__ srcv, float* __restrict__ out)
{
    int i = blockIdx.x;
    int c = threadIdx.x;  // HDIM = 256
    float acc = 0.f;
    int e0 = offs[i], e1 = offs[i + 1];
    __shared__ int sS[16];
    __shared__ float sD[16];
    for (int base = e0; base < e1; base += 16) {
        int g = min(16, e1 - base);
        __syncthreads();
        if (threadIdx.x < g) {
            int e = eid[base + threadIdx.x];
            int s = srcv[e];
            sS[threadIdx.x] = s;
            sD[threadIdx.x] = dinv[s];
        }
        __syncthreads();
        for (int j = 0; j < g; j++)
            acc += sD[j] * h[(size_t)sS[j] * HDIM + c];
    }
    float di = dinv[i];
    out[(size_t)i * HDIM + c] = fmaxf(di * acc + di * di * h[(size_t)i * HDIM + c] + bias[c], 0.f);
}

// ---------------- goal-feature rank-1 precompute: cg[c] = d1_b[c] + sum_k g[k]*d1_W[256+k][c] ----------------
__global__ void k_goalvec(const float* __restrict__ g, const float* __restrict__ W,
                          const float* __restrict__ b, float* __restrict__ cg) {
    int c = blockIdx.x * blockDim.x + threadIdx.x;
    if (c >= DIM) return;
    float acc = b[c];
    for (int k = 0; k < DIM; k++)
        acc += g[k] * W[(size_t)(HDIM + k) * DIM + c];
    cg[c] = acc;
}

// ---------------- final dot: out[i] = hd[i] . d2_W + d2_b ----------------
__global__ __launch_bounds__(256) void k_final(const float* __restrict__ hd,
                                               const float* __restrict__ w2,
                                               const float* __restrict__ b2,
                                               float* __restrict__ out) {
    int wave = threadIdx.x >> 6, lane = threadIdx.x & 63;
    int i = blockIdx.x * 4 + wave;
    if (i >= N_NODES) return;
    const float* r = hd + (size_t)i * DIM;
    float acc = 0.f;
#pragma unroll
    for (int q = 0; q < 8; q++) acc += r[lane + 64 * q] * w2[lane + 64 * q];
#pragma unroll
    for (int off = 32; off > 0; off >>= 1) acc += __shfl_down(acc, off, 64);
    if (lane == 0) out[i] = acc + b2[0];
}

// ---------------- launch ----------------
extern "C" void kernel_launch(void* const* d_in, const int* in_sizes, int n_in,
                              void* d_out, int out_size, void* d_ws, size_t ws_size,
                              hipStream_t stream) {
    (void)in_sizes; (void)n_in; (void)out_size; (void)ws_size;
    const float* x        = (const float*)d_in[0];
    const float* ea       = (const float*)d_in[1];
    const float* goal     = (const float*)d_in[2];
    const float* cgWf[2]  = {(const float*)d_in[3],  (const float*)d_in[11]};
    const float* cgbf[2]  = {(const float*)d_in[4],  (const float*)d_in[12]};
    const float* cgWs[2]  = {(const float*)d_in[5],  (const float*)d_in[13]};
    const float* cgbs[2]  = {(const float*)d_in[6],  (const float*)d_in[14]};
    const float* cggm[2]  = {(const float*)d_in[7],  (const float*)d_in[15]};
    const float* cgbt[2]  = {(const float*)d_in[8],  (const float*)d_in[16]};
    const float* cgmn[2]  = {(const float*)d_in[9],  (const float*)d_in[17]};
    const float* cgvr[2]  = {(const float*)d_in[10], (const float*)d_in[18]};
    const float* gcn3_W = (const float*)d_in[19];
    const float* gcn3_b = (const float*)d_in[20];
    const float* gcn4_W = (const float*)d_in[21];
    const float* gcn4_b = (const float*)d_in[22];
    const float* d1_W   = (const float*)d_in[23];
    const float* d1_b   = (const float*)d_in[24];
    const float* d2_W   = (const float*)d_in[25];
    const float* d2_b   = (const float*)d_in[26];
    const int*   eidx   = (const int*)d_in[27];
    const int*   srcv   = eidx;
    const int*   dstv   = eidx + N_EDGES;
    float* outp = (float*)d_out;

    const size_t ND = (size_t)N_NODES * DIM;
    float* ws  = (float*)d_ws;
    float* xA  = ws;
    float* xB  = xA + ND;
    float* Pf  = xB + ND;
    float* Qf  = Pf + ND;
    float* Ps  = Qf + ND;
    float* Qs  = Ps + ND;
    float* cgv = Qs + ND;                       // 512
    int* offs   = (int*)(cgv + DIM);            // N+1
    int* cursor = offs + (N_NODES + 1);         // N
    int* eidArr = cursor + N_NODES;             // E
    float* dinv = (float*)(eidArr + N_EDGES);   // N
    // buffer aliases for the tail of the net (P/Q free after cg2)
    float* h3 = Pf;   // N x 256
    float* x3 = Qf;   // N x 256
    float* h4 = Ps;   // N x 256
    float* x4 = Qs;   // N x 256
    float* hd = xB;   // N x 512

    // CSR build
    hipMemsetAsync(offs, 0, (N_NODES + 1) * sizeof(int), stream);
    hipMemsetAsync(cursor, 0, N_NODES * sizeof(int), stream);
    k_hist<<<(N_EDGES + 255) / 256, 256, 0, stream>>>(dstv, offs);
    k_scan<<<1, 1024, 0, stream>>>(offs, dinv);
    k_scatter<<<(N_EDGES + 255) / 256, 256, 0, stream>>>(dstv, offs, cursor, eidArr);

    dim3 g512((N_NODES + BM - 1) / BM, DIM / BNT);
    dim3 g256((N_NODES + BM - 1) / BM, HDIM / BNT);

    // two CGConv layers
    const float* xin = x;
    float* xout = xB;
    for (int l = 0; l < 2; l++) {
        k_gemm<<<g512, 256, 0, stream>>>(xin, N_NODES, DIM, cgWf[l],            DIM, cgbf[l], Pf, DIM, 0);
        k_gemm<<<g512, 256, 0, stream>>>(xin, N_NODES, DIM, cgWf[l] + DIM * DIM, DIM, nullptr, Qf, DIM, 0);
        k_gemm<<<g512, 256, 0, stream>>>(xin, N_NODES, DIM, cgWs[l],            DIM, cgbs[l], Ps, DIM, 0);
        k_gemm<<<g512, 256, 0, stream>>>(xin, N_NODES, DIM, cgWs[l] + DIM * DIM, DIM, nullptr, Qs, DIM, 0);
        k_cg_aggr<<<N_NODES, 256, 0, stream>>>(xin, Pf, Qf, Ps, Qs,
                                               cgWf[l] + 2 * DIM * DIM, cgWs[l] + 2 * DIM * DIM,
                                               cggm[l], cgbt[l], cgmn[l], cgvr[l],
                                               offs, eidArr, srcv, ea, xout);
        xin = xout;           // after l=0: xin = xB
        xout = xA;            // l=1 writes xA
    }
    // xA holds x after cg2+relu

    // GCN layer 3: 512 -> 256
    k_gemm<<<g256, 256, 0, stream>>>(xA, N_NODES, DIM, gcn3_W, HDIM, nullptr, h3, HDIM, 0);
    k_gcn_aggr<<<N_NODES, 256, 0, stream>>>(h3, dinv, gcn3_b, offs, eidArr, srcv, x3);
    // GCN layer 4: 256 -> 256
    k_gemm<<<g256, 256, 0, stream>>>(x3, N_NODES, HDIM, gcn4_W, HDIM, nullptr, h4, HDIM, 0);
    k_gcn_aggr<<<N_NODES, 256, 0, stream>>>(h4, dinv, gcn4_b, offs, eidArr, srcv, x4);

    // dense head
    k_goalvec<<<2, 256, 0, stream>>>(goal, d1_W, d1_b, cgv);
    k_gemm<<<g512, 256, 0, stream>>>(x4, N_NODES, HDIM, d1_W, DIM, cgv, hd, DIM, 1);
    k_final<<<(N_NODES + 3) / 4, 256, 0, stream>>>(hd, d2_W, d2_b, outp);
}

// Round 2
// 1056.782 us; speedup vs baseline: 1.5132x; 1.5132x over previous
//
#include <hip/hip_runtime.h>

#define N_NODES 10000
#define N_EDGES 160000
#define DIM 512
#define HDIM 256
#define EDIM 16
#define BN_EPS 1e-5f
#define MPAD 10112  // 79*128

typedef unsigned short ushort_t;
typedef unsigned int uint_t;
typedef __attribute__((ext_vector_type(8))) short bf16x8;
typedef __attribute__((ext_vector_type(4))) float f32x4;

// ---------------- helpers ----------------
__device__ __forceinline__ float sigmoid_f(float x) {
    return 1.0f / (1.0f + __expf(-x));
}
__device__ __forceinline__ float softplus_f(float x) {
    return fmaxf(x, 0.0f) + __logf(1.0f + __expf(-fabsf(x)));
}
__device__ __forceinline__ ushort_t f2bf(float x) {
    uint_t u = __float_as_uint(x);
    uint_t r = (u + 0x7FFF + ((u >> 16) & 1)) >> 16;  // RNE
    return (ushort_t)r;
}
__device__ __forceinline__ float bf2f(ushort_t h) {
    return __uint_as_float(((uint_t)h) << 16);
}
__device__ __forceinline__ void gld16(const void* g, void* l) {
    __builtin_amdgcn_global_load_lds(
        (const __attribute__((address_space(1))) unsigned int*)g,
        (__attribute__((address_space(3))) unsigned int*)l, 16, 0, 0);
}

// ---------------- CSR build ----------------
__global__ void k_hist(const int* __restrict__ dst, int* __restrict__ cnt) {
    int e = blockIdx.x * blockDim.x + threadIdx.x;
    if (e < N_EDGES) atomicAdd(&cnt[dst[e]], 1);
}

__global__ __launch_bounds__(1024) void k_scan(int* __restrict__ offs, float* __restrict__ dinv) {
    __shared__ int sbuf[1024];
    __shared__ int carry;
    if (threadIdx.x == 0) carry = 0;
    __syncthreads();
    for (int base = 0; base < N_NODES; base += 1024) {
        int idx = base + threadIdx.x;
        int v = (idx < N_NODES) ? offs[idx] : 0;
        if (idx < N_NODES) dinv[idx] = rsqrtf((float)v + 1.0f);
        sbuf[threadIdx.x] = v;
        __syncthreads();
        for (int off = 1; off < 1024; off <<= 1) {
            int t = (threadIdx.x >= off) ? sbuf[threadIdx.x - off] : 0;
            __syncthreads();
            sbuf[threadIdx.x] += t;
            __syncthreads();
        }
        if (idx < N_NODES) offs[idx] = carry + sbuf[threadIdx.x] - v;
        __syncthreads();
        if (threadIdx.x == 1023) carry += sbuf[1023];
        __syncthreads();
    }
    if (threadIdx.x == 0) offs[N_NODES] = carry;
}

__global__ void k_scatter(const int* __restrict__ dst, const int* __restrict__ offs,
                          int* __restrict__ cursor, int* __restrict__ eid) {
    int e = blockIdx.x * blockDim.x + threadIdx.x;
    if (e < N_EDGES) {
        int d = dst[e];
        int p = offs[d] + atomicAdd(&cursor[d], 1);
        eid[p] = e;
    }
}

// ---------------- split-bf16 conversion ----------------
// X [M x K] f32 -> A2 [M x 2K] bf16 : cols [0,K)=hi, [K,2K)=lo
__global__ void k_cvtA(const float* __restrict__ X, int MK, int kshift,
                       ushort_t* __restrict__ A2) {
    int idx = blockIdx.x * 256 + threadIdx.x;
    if (idx >= MK) return;
    int K = 1 << kshift;
    int m = idx >> kshift, k = idx & (K - 1);
    float x = X[idx];
    ushort_t hi = f2bf(x);
    ushort_t lo = f2bf(x - bf2f(hi));
    size_t rb = (size_t)m * (K << 1);
    A2[rb + k] = hi;
    A2[rb + K + k] = lo;
}

// CG weights -> W2t [2048 cols][1536 k], col groups [Pf|Ps|Qf|Qs],
// k blocks: [0,512)=hi, [512,1024)=hi, [1024,1536)=lo
// grid (6, 2048)
__global__ void k_cvtW_cg(const float* __restrict__ Wf, const float* __restrict__ Ws,
                          ushort_t* __restrict__ W2t) {
    int k = blockIdx.x * 256 + threadIdx.x;  // 0..1535
    int c2 = blockIdx.y;                     // 0..2047
    int part = k >> 9;
    int kk = k & 511;
    int g = c2 >> 9, c = c2 & 511;
    const float* W = (g & 1) ? Ws : Wf;
    int roff = (g & 2) ? 512 : 0;
    float x = W[(size_t)(roff + kk) * 512 + c];
    ushort_t hi = f2bf(x);
    ushort_t out = (part == 2) ? f2bf(x - bf2f(hi)) : hi;
    W2t[(size_t)c2 * 1536 + k] = out;
}

// plain weight [KH x ncols] (ldw) -> W2t [ncols][3*KH]; grid (3*KH/256, ncols)
__global__ void k_cvtW_plain(const float* __restrict__ W, int ldw, int khshift,
                             ushort_t* __restrict__ W2t) {
    int k = blockIdx.x * 256 + threadIdx.x;
    int c = blockIdx.y;
    int KH = 1 << khshift;
    int part = k >> khshift;
    int kk = k & (KH - 1);
    float x = W[(size_t)kk * ldw + c];
    ushort_t hi = f2bf(x);
    ushort_t out = (part == 2) ? f2bf(x - bf2f(hi)) : hi;
    W2t[(size_t)c * 3 * KH + k] = out;
}

// ---------------- bf16 MFMA GEMM (split 3-term via K concatenation) ----------------
// C[M x ncols] = A2 [M x 2KH](hi|lo; 3rd k-block re-reads hi) @ W2t [ncols][3KH]
// mode 0: fp32 C, ldc.  mode 1: CG (cols<1024 -> outF f32 ld 1024; cols>=1024 -> outQ bf16 ld 1024)
// mode 2: fp32 relu(C + bias[col]), ldc
__global__ __launch_bounds__(256) void k_gemm3(
    const ushort_t* __restrict__ A2, int lda, int KH, int M,
    const ushort_t* __restrict__ W2t,
    float* __restrict__ outF, ushort_t* __restrict__ outQ,
    const float* __restrict__ bias, int mode, int ldc)
{
    __shared__ ushort_t As[128 * 32];
    __shared__ ushort_t Bs[128 * 32];
    const int Ktot = 3 * KH;
    int tid = threadIdx.x;
    int lane = tid & 63, w = tid >> 6;
    int wm = w & 1, wn = w >> 1;
    int lrow = lane & 15, quad = lane >> 4;
    int row0 = blockIdx.x * 128, col0 = blockIdx.y * 128;

    f32x4 acc[4][4] = {};

    // staging: slot s (16B granule): tile row = s>>2, phys kq = s&3,
    // logical kq = (s&3) ^ ((row>>1)&3)  [2-way-free xor swizzle]
    int s0 = tid, s1 = 256 + tid;
    int r0 = s0 >> 2, kq0 = (s0 & 3) ^ ((r0 >> 1) & 3);
    int r1 = s1 >> 2, kq1 = (s1 & 3) ^ ((r1 >> 1) & 3);
    const ushort_t* Ar0 = A2 + (size_t)(row0 + r0) * lda + kq0 * 8;
    const ushort_t* Ar1 = A2 + (size_t)(row0 + r1) * lda + kq1 * 8;
    const ushort_t* Br0 = W2t + (size_t)(col0 + r0) * Ktot + kq0 * 8;
    const ushort_t* Br1 = W2t + (size_t)(col0 + r1) * Ktot + kq1 * 8;
    ushort_t* Al0 = As + s0 * 8; ushort_t* Al1 = As + s1 * 8;
    ushort_t* Bl0 = Bs + s0 * 8; ushort_t* Bl1 = Bs + s1 * 8;

    // fragment LDS addresses (apply same swizzle)
    const ushort_t* afp[4];
    const ushort_t* bfp[4];
#pragma unroll
    for (int mt = 0; mt < 4; mt++) {
        int r = wm * 64 + mt * 16 + lrow;
        afp[mt] = As + r * 32 + ((quad ^ ((r >> 1) & 3)) * 8);
        int c = wn * 64 + mt * 16 + lrow;
        bfp[mt] = Bs + c * 32 + ((quad ^ ((c >> 1) & 3)) * 8);
    }

    for (int k0 = 0; k0 < Ktot; k0 += 32) {
        int ak = (k0 < 2 * KH) ? k0 : k0 - 2 * KH;  // 3rd block re-reads hi
        __syncthreads();
        gld16(Ar0 + ak, Al0);
        gld16(Ar1 + ak, Al1);
        gld16(Br0 + k0, Bl0);
        gld16(Br1 + k0, Bl1);
        __syncthreads();
        bf16x8 af[4], bff[4];
#pragma unroll
        for (int i = 0; i < 4; i++) {
            af[i]  = *(const bf16x8*)afp[i];
            bff[i] = *(const bf16x8*)bfp[i];
        }
#pragma unroll
        for (int mt = 0; mt < 4; mt++)
#pragma unroll
            for (int nt = 0; nt < 4; nt++)
                acc[mt][nt] = __builtin_amdgcn_mfma_f32_16x16x32_bf16(
                    af[mt], bff[nt], acc[mt][nt], 0, 0, 0);
    }

#pragma unroll
    for (int mt = 0; mt < 4; mt++) {
#pragma unroll
        for (int nt = 0; nt < 4; nt++) {
            int gcol = col0 + wn * 64 + nt * 16 + lrow;
#pragma unroll
            for (int r = 0; r < 4; r++) {
                int grow = row0 + wm * 64 + mt * 16 + quad * 4 + r;
                if (grow >= M) continue;
                float v = acc[mt][nt][r];
                if (mode == 2) v = fmaxf(v + bias[gcol], 0.f);
                if (mode == 1) {
                    if (gcol < 1024) outF[(size_t)grow * 1024 + gcol] = v;
                    else outQ[(size_t)grow * 1024 + (gcol - 1024)] = f2bf(v);
                } else {
                    outF[(size_t)grow * ldc + gcol] = v;
                }
            }
        }
    }
}

// ---------------- CGConv aggregation + BN + residual + ReLU ----------------
// P [N x 1024] f32 = [Pf|Ps]; Q [N x 1024] bf16 = [Qf|Qs]
__global__ __launch_bounds__(256) void k_cg_aggr(
    const float* __restrict__ xin, const float* __restrict__ P,
    const ushort_t* __restrict__ Q,
    const float* __restrict__ WfE, const float* __restrict__ WsE,
    const float* __restrict__ bfv, const float* __restrict__ bsv,
    const float* __restrict__ gamma, const float* __restrict__ beta,
    const float* __restrict__ mean, const float* __restrict__ var,
    const int* __restrict__ offs, const int* __restrict__ eid,
    const int* __restrict__ srcv, const float* __restrict__ ea,
    float* __restrict__ xout)
{
    int i = blockIdx.x;
    int t = threadIdx.x;
    int c0 = 2 * t;
    float2 wf[EDIM], wsr[EDIM];
#pragma unroll
    for (int k = 0; k < EDIM; k++) {
        wf[k]  = *(const float2*)&WfE[k * DIM + c0];
        wsr[k] = *(const float2*)&WsE[k * DIM + c0];
    }
    float2 pf = *(const float2*)&P[(size_t)i * 1024 + c0];
    float2 ps = *(const float2*)&P[(size_t)i * 1024 + 512 + c0];
    pf.x += bfv[c0]; pf.y += bfv[c0 + 1];
    ps.x += bsv[c0]; ps.y += bsv[c0 + 1];
    float acc0 = 0.f, acc1 = 0.f;
    int e0 = offs[i], e1 = offs[i + 1];
    __shared__ float sEa[16][EDIM];
    __shared__ int sSrc[16];
    for (int base = e0; base < e1; base += 16) {
        int g = min(16, e1 - base);
        __syncthreads();
        if (t < g * 16) {
            int j = t >> 4, k = t & 15;
            int e = eid[base + j];
            sEa[j][k] = ea[(size_t)e * EDIM + k];
            if (k == 0) sSrc[j] = srcv[e];
        }
        __syncthreads();
        for (int j = 0; j < g; j++) {
            int s = sSrc[j];
            uint_t qf = *(const uint_t*)&Q[(size_t)s * 1024 + c0];
            uint_t qs = *(const uint_t*)&Q[(size_t)s * 1024 + 512 + c0];
            float gf0 = pf.x + bf2f((ushort_t)(qf & 0xffff));
            float gf1 = pf.y + bf2f((ushort_t)(qf >> 16));
            float gs0 = ps.x + bf2f((ushort_t)(qs & 0xffff));
            float gs1 = ps.y + bf2f((ushort_t)(qs >> 16));
#pragma unroll
            for (int k = 0; k < EDIM; k++) {
                float a = sEa[j][k];
                gf0 += a * wf[k].x;  gf1 += a * wf[k].y;
                gs0 += a * wsr[k].x; gs1 += a * wsr[k].y;
            }
            acc0 += sigmoid_f(gf0) * softplus_f(gs0);
            acc1 += sigmoid_f(gf1) * softplus_f(gs1);
        }
    }
    size_t ib = (size_t)i * DIM;
    float bn0 = (acc0 - mean[c0])     * rsqrtf(var[c0]     + BN_EPS) * gamma[c0]     + beta[c0];
    float bn1 = (acc1 - mean[c0 + 1]) * rsqrtf(var[c0 + 1] + BN_EPS) * gamma[c0 + 1] + beta[c0 + 1];
    float o0 = fmaxf(xin[ib + c0] + bn0, 0.f);
    float o1 = fmaxf(xin[ib + c0 + 1] + bn1, 0.f);
    xout[ib + c0] = o0;
    xout[ib + c0 + 1] = o1;
}

// ---------------- GCN aggregation ----------------
__global__ __launch_bounds__(256) void k_gcn_aggr(
    const float* __restrict__ h, const float* __restrict__ dinv,
    const float* __restrict__ bias,
    const int* __restrict__ offs, const int* __restrict__ eid,
    const int* __restrict__ srcv, float* __restrict__ out)
{
    int i = blockIdx.x;
    int c = threadIdx.x;
    float acc = 0.f;
    int e0 = offs[i], e1 = offs[i + 1];
    __shared__ int sS[16];
    __shared__ float sD[16];
    for (int base = e0; base < e1; base += 16) {
        int g = min(16, e1 - base);
        __syncthreads();
        if (threadIdx.x < g) {
            int e = eid[base + threadIdx.x];
            int s = srcv[e];
            sS[threadIdx.x] = s;
            sD[threadIdx.x] = dinv[s];
        }
        __syncthreads();
        for (int j = 0; j < g; j++)
            acc += sD[j] * h[(size_t)sS[j] * HDIM + c];
    }
    float di = dinv[i];
    out[(size_t)i * HDIM + c] = fmaxf(di * acc + di * di * h[(size_t)i * HDIM + c] + bias[c], 0.f);
}

// ---------------- goal-feature rank-1 precompute ----------------
__global__ void k_goalvec(const float* __restrict__ g, const float* __restrict__ W,
                          const float* __restrict__ b, float* __restrict__ cg) {
    int c = blockIdx.x * blockDim.x + threadIdx.x;
    if (c >= DIM) return;
    float acc = b[c];
    for (int k = 0; k < DIM; k++)
        acc += g[k] * W[(size_t)(HDIM + k) * DIM + c];
    cg[c] = acc;
}

// ---------------- final dot ----------------
__global__ __launch_bounds__(256) void k_final(const float* __restrict__ hd,
                                               const float* __restrict__ w2,
                                               const float* __restrict__ b2,
                                               float* __restrict__ out) {
    int wave = threadIdx.x >> 6, lane = threadIdx.x & 63;
    int i = blockIdx.x * 4 + wave;
    if (i >= N_NODES) return;
    const float* r = hd + (size_t)i * DIM;
    float acc = 0.f;
#pragma unroll
    for (int q = 0; q < 8; q++) acc += r[lane + 64 * q] * w2[lane + 64 * q];
#pragma unroll
    for (int off = 32; off > 0; off >>= 1) acc += __shfl_down(acc, off, 64);
    if (lane == 0) out[i] = acc + b2[0];
}

// ---------------- launch ----------------
extern "C" void kernel_launch(void* const* d_in, const int* in_sizes, int n_in,
                              void* d_out, int out_size, void* d_ws, size_t ws_size,
                              hipStream_t stream) {
    (void)in_sizes; (void)n_in; (void)out_size; (void)ws_size;
    const float* x      = (const float*)d_in[0];
    const float* ea     = (const float*)d_in[1];
    const float* goal   = (const float*)d_in[2];
    const float* cgWf[2] = {(const float*)d_in[3],  (const float*)d_in[11]};
    const float* cgbf[2] = {(const float*)d_in[4],  (const float*)d_in[12]};
    const float* cgWs[2] = {(const float*)d_in[5],  (const float*)d_in[13]};
    const float* cgbs[2] = {(const float*)d_in[6],  (const float*)d_in[14]};
    const float* cggm[2] = {(const float*)d_in[7],  (const float*)d_in[15]};
    const float* cgbt[2] = {(const float*)d_in[8],  (const float*)d_in[16]};
    const float* cgmn[2] = {(const float*)d_in[9],  (const float*)d_in[17]};
    const float* cgvr[2] = {(const float*)d_in[10], (const float*)d_in[18]};
    const float* gcn3_W = (const float*)d_in[19];
    const float* gcn3_b = (const float*)d_in[20];
    const float* gcn4_W = (const float*)d_in[21];
    const float* gcn4_b = (const float*)d_in[22];
    const float* d1_W   = (const float*)d_in[23];
    const float* d1_b   = (const float*)d_in[24];
    const float* d2_W   = (const float*)d_in[25];
    const float* d2_b   = (const float*)d_in[26];
    const int*   eidx   = (const int*)d_in[27];
    const int*   srcv   = eidx;
    const int*   dstv   = eidx + N_EDGES;
    float* outp = (float*)d_out;

    // ---- workspace layout (~110 MB) ----
    float*    Pbuf = (float*)d_ws;                                  // 10000*1024 f32
    ushort_t* Qbuf = (ushort_t*)(Pbuf + (size_t)N_NODES * 1024);    // 10000*1024 bf16
    float*    xB   = (float*)(Qbuf + (size_t)N_NODES * 1024);       // 10000*512 f32
    ushort_t* A2   = (ushort_t*)(xB + (size_t)N_NODES * DIM);       // 10112*1024 bf16
    ushort_t* W2t  = A2 + (size_t)MPAD * 1024;                      // 2048*1536 bf16
    float*    cgv  = (float*)(W2t + (size_t)2048 * 1536);           // 512
    int* offs   = (int*)(cgv + DIM);            // N+1
    int* cursor = offs + (N_NODES + 1);         // N
    int* eidArr = cursor + N_NODES;             // E
    float* dinv = (float*)(eidArr + N_EDGES);   // N
    // tail-phase aliases (Pbuf/Qbuf free after CG layers)
    float* h3 = Pbuf;
    float* x3 = Pbuf + (size_t)N_NODES * HDIM;
    float* h4 = Pbuf + (size_t)2 * N_NODES * HDIM;
    float* x4 = Pbuf + (size_t)3 * N_NODES * HDIM;
    float* hd = (float*)Qbuf;                   // 10000*512 f32 (fits exactly)

    // ---- CSR build ----
    hipMemsetAsync(offs, 0, (N_NODES + 1) * sizeof(int), stream);
    hipMemsetAsync(cursor, 0, N_NODES * sizeof(int), stream);
    k_hist<<<(N_EDGES + 255) / 256, 256, 0, stream>>>(dstv, offs);
    k_scan<<<1, 1024, 0, stream>>>(offs, dinv);
    k_scatter<<<(N_EDGES + 255) / 256, 256, 0, stream>>>(dstv, offs, cursor, eidArr);

    const int MKA512 = N_NODES * 512;   // cvtA elems for K=512
    const int MKA256 = N_NODES * 256;

    // ---- CG layer 1 ----
    k_cvtA<<<(MKA512 + 255) / 256, 256, 0, stream>>>(x, MKA512, 9, A2);
    k_cvtW_cg<<<dim3(6, 2048), 256, 0, stream>>>(cgWf[0], cgWs[0], W2t);
    k_gemm3<<<dim3(79, 16), 256, 0, stream>>>(A2, 1024, 512, N_NODES, W2t,
                                              Pbuf, Qbuf, nullptr, 1, 0);
    k_cg_aggr<<<N_NODES, 256, 0, stream>>>(x, Pbuf, Qbuf,
                                           cgWf[0] + 1024 * 512, cgWs[0] + 1024 * 512,
                                           cgbf[0], cgbs[0],
                                           cggm[0], cgbt[0], cgmn[0], cgvr[0],
                                           offs, eidArr, srcv, ea, xB);
    // ---- CG layer 2 (in-place on xB) ----
    k_cvtA<<<(MKA512 + 255) / 256, 256, 0, stream>>>(xB, MKA512, 9, A2);
    k_cvtW_cg<<<dim3(6, 2048), 256, 0, stream>>>(cgWf[1], cgWs[1], W2t);
    k_gemm3<<<dim3(79, 16), 256, 0, stream>>>(A2, 1024, 512, N_NODES, W2t,
                                              Pbuf, Qbuf, nullptr, 1, 0);
    k_cg_aggr<<<N_NODES, 256, 0, stream>>>(xB, Pbuf, Qbuf,
                                           cgWf[1] + 1024 * 512, cgWs[1] + 1024 * 512,
                                           cgbf[1], cgbs[1],
                                           cggm[1], cgbt[1], cgmn[1], cgvr[1],
                                           offs, eidArr, srcv, ea, xB);

    // ---- GCN 3: 512 -> 256 ----
    k_cvtA<<<(MKA512 + 255) / 256, 256, 0, stream>>>(xB, MKA512, 9, A2);
    k_cvtW_plain<<<dim3(6, 256), 256, 0, stream>>>(gcn3_W, HDIM, 9, W2t);
    k_gemm3<<<dim3(79, 2), 256, 0, stream>>>(A2, 1024, 512, N_NODES, W2t,
                                             h3, nullptr, nullptr, 0, HDIM);
    k_gcn_aggr<<<N_NODES, 256, 0, stream>>>(h3, dinv, gcn3_b, offs, eidArr, srcv, x3);

    // ---- GCN 4: 256 -> 256 ----
    k_cvtA<<<(MKA256 + 255) / 256, 256, 0, stream>>>(x3, MKA256, 8, A2);
    k_cvtW_plain<<<dim3(3, 256), 256, 0, stream>>>(gcn4_W, HDIM, 8, W2t);
    k_gemm3<<<dim3(79, 2), 256, 0, stream>>>(A2, 512, 256, N_NODES, W2t,
                                             h4, nullptr, nullptr, 0, HDIM);
    k_gcn_aggr<<<N_NODES, 256, 0, stream>>>(h4, dinv, gcn4_b, offs, eidArr, srcv, x4);

    // ---- dense head ----
    k_goalvec<<<2, 256, 0, stream>>>(goal, d1_W, d1_b, cgv);
    k_cvtA<<<(MKA256 + 255) / 256, 256, 0, stream>>>(x4, MKA256, 8, A2);
    k_cvtW_plain<<<dim3(3, 512), 256, 0, stream>>>(d1_W, DIM, 8, W2t);
    k_gemm3<<<dim3(79, 4), 256, 0, stream>>>(A2, 512, 256, N_NODES, W2t,
                                             hd, nullptr, cgv, 2, DIM);
    k_final<<<(N_NODES + 3) / 4, 256, 0, stream>>>(hd, d2_W, d2_b, outp);
}

// Round 4
// 880.948 us; speedup vs baseline: 1.8152x; 1.1996x over previous
//
#include <hip/hip_runtime.h>

#define N_NODES 10000
#define N_EDGES 160000
#define DIM 512
#define HDIM 256
#define EDIM 16
#define BN_EPS 1e-5f
#define MPAD 10112  // 79*128

typedef unsigned short ushort_t;
typedef unsigned int uint_t;
typedef __attribute__((ext_vector_type(8))) short bf16x8;
typedef __attribute__((ext_vector_type(4))) float f32x4;
typedef __attribute__((ext_vector_type(2))) _Float16 half2_t;

// ---------------- helpers ----------------
__device__ __forceinline__ ushort_t f2bf(float x) {
    uint_t u = __float_as_uint(x);
    uint_t r = (u + 0x7FFF + ((u >> 16) & 1)) >> 16;  // RNE
    return (ushort_t)r;
}
__device__ __forceinline__ float bf2f(ushort_t h) {
    return __uint_as_float(((uint_t)h) << 16);
}
__device__ __forceinline__ float bflo(uint_t u) {  // low bf16 of packed u32
    return __uint_as_float(u << 16);
}
__device__ __forceinline__ float bfhi(uint_t u) {  // high bf16 of packed u32
    return __uint_as_float(u & 0xffff0000u);
}
__device__ __forceinline__ void gld16(const void* g, void* l) {
    __builtin_amdgcn_global_load_lds(
        (const __attribute__((address_space(1))) unsigned int*)g,
        (__attribute__((address_space(3))) unsigned int*)l, 16, 0, 0);
}
__device__ __forceinline__ half2_t u2h(uint_t u) {
    return __builtin_bit_cast(half2_t, u);
}
__device__ __forceinline__ uint_t pk_f16(float a, float b) {
    return __builtin_bit_cast(uint_t, __builtin_amdgcn_cvt_pkrtz(a, b));
}

// ---------------- CSR build ----------------
__global__ void k_hist(const int* __restrict__ dst, int* __restrict__ cnt) {
    int e = blockIdx.x * blockDim.x + threadIdx.x;
    if (e < N_EDGES) atomicAdd(&cnt[dst[e]], 1);
}

__global__ __launch_bounds__(1024) void k_scan(int* __restrict__ offs, float* __restrict__ dinv) {
    __shared__ int sbuf[1024];
    __shared__ int carry;
    if (threadIdx.x == 0) carry = 0;
    __syncthreads();
    for (int base = 0; base < N_NODES; base += 1024) {
        int idx = base + threadIdx.x;
        int v = (idx < N_NODES) ? offs[idx] : 0;
        if (idx < N_NODES) dinv[idx] = rsqrtf((float)v + 1.0f);
        sbuf[threadIdx.x] = v;
        __syncthreads();
        for (int off = 1; off < 1024; off <<= 1) {
            int t = (threadIdx.x >= off) ? sbuf[threadIdx.x - off] : 0;
            __syncthreads();
            sbuf[threadIdx.x] += t;
            __syncthreads();
        }
        if (idx < N_NODES) offs[idx] = carry + sbuf[threadIdx.x] - v;
        __syncthreads();
        if (threadIdx.x == 1023) carry += sbuf[1023];
        __syncthreads();
    }
    if (threadIdx.x == 0) offs[N_NODES] = carry;
}

__global__ void k_scatter(const int* __restrict__ dst, const int* __restrict__ offs,
                          int* __restrict__ cursor, int* __restrict__ eid) {
    int e = blockIdx.x * blockDim.x + threadIdx.x;
    if (e < N_EDGES) {
        int d = dst[e];
        int p = offs[d] + atomicAdd(&cursor[d], 1);
        eid[p] = e;
    }
}

// ---------------- conversions ----------------
// X [M x K] f32 -> A2 [M x 2K] bf16 : cols [0,K)=hi, [K,2K)=lo
__global__ void k_cvtA(const float* __restrict__ X, int MK, int kshift,
                       ushort_t* __restrict__ A2) {
    int idx = blockIdx.x * 256 + threadIdx.x;
    if (idx >= MK) return;
    int K = 1 << kshift;
    int m = idx >> kshift, k = idx & (K - 1);
    float x = X[idx];
    ushort_t hi = f2bf(x);
    ushort_t lo = f2bf(x - bf2f(hi));
    size_t rb = (size_t)m * (K << 1);
    A2[rb + k] = hi;
    A2[rb + K + k] = lo;
}

// CG weights -> W2t [2048 cols][1536 k], col groups [Pf|Ps|Qf|Qs]
__global__ void k_cvtW_cg(const float* __restrict__ Wf, const float* __restrict__ Ws,
                          ushort_t* __restrict__ W2t) {
    int k = blockIdx.x * 256 + threadIdx.x;  // 0..1535
    int c2 = blockIdx.y;                     // 0..2047
    int part = k >> 9;
    int kk = k & 511;
    int g = c2 >> 9, c = c2 & 511;
    const float* W = (g & 1) ? Ws : Wf;
    int roff = (g & 2) ? 512 : 0;
    float x = W[(size_t)(roff + kk) * 512 + c];
    ushort_t hi = f2bf(x);
    ushort_t out = (part == 2) ? f2bf(x - bf2f(hi)) : hi;
    W2t[(size_t)c2 * 1536 + k] = out;
}

// plain weight [KH x ncols] (ldw) -> W2t [ncols][3*KH]; grid (3*KH/256, ncols)
__global__ void k_cvtW_plain(const float* __restrict__ W, int ldw, int khshift,
                             ushort_t* __restrict__ W2t) {
    int k = blockIdx.x * 256 + threadIdx.x;
    int c = blockIdx.y;
    int KH = 1 << khshift;
    int part = k >> khshift;
    int kk = k & (KH - 1);
    float x = W[(size_t)kk * ldw + c];
    ushort_t hi = f2bf(x);
    ushort_t out = (part == 2) ? f2bf(x - bf2f(hi)) : hi;
    W2t[(size_t)c * 3 * KH + k] = out;
}

// edge-weight block [16 x 512] f32 -> packed f16 pairs, layout [ch][k2] u32 (8 per ch)
__global__ void k_prep_wep(const float* __restrict__ Wf, const float* __restrict__ Ws,
                           uint_t* __restrict__ WEPf, uint_t* __restrict__ WEPs) {
    int idx = blockIdx.x * 256 + threadIdx.x;  // 4096
    if (idx >= 4096) return;
    int c = idx >> 3, k2 = idx & 7;
    WEPf[c * 8 + k2] = pk_f16(Wf[(2 * k2) * 512 + c], Wf[(2 * k2 + 1) * 512 + c]);
    WEPs[c * 8 + k2] = pk_f16(Ws[(2 * k2) * 512 + c], Ws[(2 * k2 + 1) * 512 + c]);
}

// ---------------- bf16 MFMA GEMM (split 3-term via K concatenation) ----------------
// mode 1: CG (cols<1024 -> outF f32 ld 1024; cols>=1024 -> outQ interleaved bf16 ld 1024)
// mode 2: outF = relu(v + bias[gcol]) f32, ldc
// mode 3: outQ = bf16(v), ldc
__global__ __launch_bounds__(256) void k_gemm3(
    const ushort_t* __restrict__ A2, int lda, int KH, int M,
    const ushort_t* __restrict__ W2t,
    float* __restrict__ outF, ushort_t* __restrict__ outQ,
    const float* __restrict__ bias, int mode, int ldc)
{
    __shared__ ushort_t As[128 * 32];
    __shared__ ushort_t Bs[128 * 32];
    const int Ktot = 3 * KH;
    int tid = threadIdx.x;
    int lane = tid & 63, w = tid >> 6;
    int wm = w & 1, wn = w >> 1;
    int lrow = lane & 15, quad = lane >> 4;
    int row0 = blockIdx.x * 128, col0 = blockIdx.y * 128;

    f32x4 acc[4][4] = {};

    int s0 = tid, s1 = 256 + tid;
    int r0 = s0 >> 2, kq0 = (s0 & 3) ^ ((r0 >> 1) & 3);
    int r1 = s1 >> 2, kq1 = (s1 & 3) ^ ((r1 >> 1) & 3);
    const ushort_t* Ar0 = A2 + (size_t)(row0 + r0) * lda + kq0 * 8;
    const ushort_t* Ar1 = A2 + (size_t)(row0 + r1) * lda + kq1 * 8;
    const ushort_t* Br0 = W2t + (size_t)(col0 + r0) * Ktot + kq0 * 8;
    const ushort_t* Br1 = W2t + (size_t)(col0 + r1) * Ktot + kq1 * 8;
    ushort_t* Al0 = As + s0 * 8; ushort_t* Al1 = As + s1 * 8;
    ushort_t* Bl0 = Bs + s0 * 8; ushort_t* Bl1 = Bs + s1 * 8;

    const ushort_t* afp[4];
    const ushort_t* bfp[4];
#pragma unroll
    for (int mt = 0; mt < 4; mt++) {
        int r = wm * 64 + mt * 16 + lrow;
        afp[mt] = As + r * 32 + ((quad ^ ((r >> 1) & 3)) * 8);
        int c = wn * 64 + mt * 16 + lrow;
        bfp[mt] = Bs + c * 32 + ((quad ^ ((c >> 1) & 3)) * 8);
    }

    for (int k0 = 0; k0 < Ktot; k0 += 32) {
        int ak = (k0 < 2 * KH) ? k0 : k0 - 2 * KH;  // 3rd block re-reads hi
        __syncthreads();
        gld16(Ar0 + ak, Al0);
        gld16(Ar1 + ak, Al1);
        gld16(Br0 + k0, Bl0);
        gld16(Br1 + k0, Bl1);
        __syncthreads();
        bf16x8 af[4], bff[4];
#pragma unroll
        for (int i = 0; i < 4; i++) {
            af[i]  = *(const bf16x8*)afp[i];
            bff[i] = *(const bf16x8*)bfp[i];
        }
#pragma unroll
        for (int mt = 0; mt < 4; mt++)
#pragma unroll
            for (int nt = 0; nt < 4; nt++)
                acc[mt][nt] = __builtin_amdgcn_mfma_f32_16x16x32_bf16(
                    af[mt], bff[nt], acc[mt][nt], 0, 0, 0);
    }

#pragma unroll
    for (int mt = 0; mt < 4; mt++) {
#pragma unroll
        for (int nt = 0; nt < 4; nt++) {
            int gcol = col0 + wn * 64 + nt * 16 + lrow;
#pragma unroll
            for (int r = 0; r < 4; r++) {
                int grow = row0 + wm * 64 + mt * 16 + quad * 4 + r;
                if (grow >= M) continue;
                float v = acc[mt][nt][r];
                if (mode == 1) {
                    if (gcol < 1024) {
                        outF[(size_t)grow * 1024 + gcol] = v;
                    } else {
                        int c = gcol - 1024;
                        int grp = c >> 9, cc = c & 511;
                        int pos = (cc >> 1) * 4 + grp * 2 + (cc & 1);
                        outQ[(size_t)grow * 1024 + pos] = f2bf(v);
                    }
                } else if (mode == 2) {
                    outF[(size_t)grow * ldc + gcol] = fmaxf(v + bias[gcol], 0.f);
                } else {  // mode 3
                    outQ[(size_t)grow * ldc + gcol] = f2bf(v);
                }
            }
        }
    }
}

// ---------------- CGConv aggregation + BN + residual + ReLU ----------------
// P [N x 1024] f32 = [Pf|Ps]; Qi [N x 1024] bf16 interleaved [qf0,qf1,qs0,qs1,...]
// writes xout f32 AND A2out (hi/lo split, lda 1024) for the next GEMM
__global__ __launch_bounds__(256) void k_cg_aggr(
    const float* __restrict__ xin, const float* __restrict__ P,
    const ushort_t* __restrict__ Qi,
    const uint_t* __restrict__ WEPf, const uint_t* __restrict__ WEPs,
    const float* __restrict__ bfv, const float* __restrict__ bsv,
    const float* __restrict__ gamma, const float* __restrict__ beta,
    const float* __restrict__ mean, const float* __restrict__ var,
    const int* __restrict__ offs, const int* __restrict__ eid,
    const int* __restrict__ srcv, const float* __restrict__ ea,
    float* __restrict__ xout, ushort_t* __restrict__ A2out)
{
    int i = blockIdx.x;
    int t = threadIdx.x;
    int c0 = 2 * t;
    // packed f16 edge-weight columns: [2 ch][8 k-pairs]
    uint_t wfp[2][8], wsp[2][8];
    {
        const uint_t* pf8 = WEPf + c0 * 8;
        const uint_t* ps8 = WEPs + c0 * 8;
        *(uint4*)&wfp[0][0] = *(const uint4*)(pf8 + 0);
        *(uint4*)&wfp[0][4] = *(const uint4*)(pf8 + 4);
        *(uint4*)&wfp[1][0] = *(const uint4*)(pf8 + 8);
        *(uint4*)&wfp[1][4] = *(const uint4*)(pf8 + 12);
        *(uint4*)&wsp[0][0] = *(const uint4*)(ps8 + 0);
        *(uint4*)&wsp[0][4] = *(const uint4*)(ps8 + 4);
        *(uint4*)&wsp[1][0] = *(const uint4*)(ps8 + 8);
        *(uint4*)&wsp[1][4] = *(const uint4*)(ps8 + 12);
    }
    float2 pf = *(const float2*)&P[(size_t)i * 1024 + c0];
    float2 ps = *(const float2*)&P[(size_t)i * 1024 + 512 + c0];
    float2 bf2 = *(const float2*)&bfv[c0];
    float2 bs2 = *(const float2*)&bsv[c0];
    pf.x += bf2.x; pf.y += bf2.y;
    ps.x += bs2.x; ps.y += bs2.y;
    float acc0 = 0.f, acc1 = 0.f;
    int e0 = offs[i], e1 = offs[i + 1];
    __shared__ uint_t sEaP[16][8];
    __shared__ int sSrc[16];
    const ushort_t* Qbase = Qi + 4 * t;
    for (int base = e0; base < e1; base += 16) {
        int g = min(16, e1 - base);
        __syncthreads();
        if (t < 16) {
            if (t < g) sSrc[t] = srcv[eid[base + t]];
        } else if (t < 144) {
            int tt = t - 16;
            int j = tt >> 3, k2 = tt & 7;
            if (j < g) {
                int e = eid[base + j];
                float2 v = *(const float2*)&ea[(size_t)e * EDIM + 2 * k2];
                sEaP[j][k2] = pk_f16(v.x, v.y);
            }
        }
        __syncthreads();
        for (int j = 0; j < g; j++) {
            int s = sSrc[j];
            uint2 q = *(const uint2*)(Qbase + ((size_t)s << 10));
            uint4 eA = *(const uint4*)&sEaP[j][0];
            uint4 eB = *(const uint4*)&sEaP[j][4];
            float gf0 = pf.x + bflo(q.x), gf1 = pf.y + bfhi(q.x);
            float gs0 = ps.x + bflo(q.y), gs1 = ps.y + bfhi(q.y);
            uint_t ek[8] = {eA.x, eA.y, eA.z, eA.w, eB.x, eB.y, eB.z, eB.w};
#pragma unroll
            for (int k = 0; k < 8; k++) {
                half2_t e2 = u2h(ek[k]);
                gf0 = __builtin_amdgcn_fdot2(e2, u2h(wfp[0][k]), gf0, false);
                gf1 = __builtin_amdgcn_fdot2(e2, u2h(wfp[1][k]), gf1, false);
                gs0 = __builtin_amdgcn_fdot2(e2, u2h(wsp[0][k]), gs0, false);
                gs1 = __builtin_amdgcn_fdot2(e2, u2h(wsp[1][k]), gs1, false);
            }
            float sg0 = __builtin_amdgcn_rcpf(1.f + __expf(-gf0));
            float sg1 = __builtin_amdgcn_rcpf(1.f + __expf(-gf1));
            float sp0 = fmaxf(gs0, 0.f) + __logf(1.f + __expf(-fabsf(gs0)));
            float sp1 = fmaxf(gs1, 0.f) + __logf(1.f + __expf(-fabsf(gs1)));
            acc0 += sg0 * sp0;
            acc1 += sg1 * sp1;
        }
    }
    size_t ib = (size_t)i * DIM;
    float2 mn = *(const float2*)&mean[c0];
    float2 vr = *(const float2*)&var[c0];
    float2 gm = *(const float2*)&gamma[c0];
    float2 bt = *(const float2*)&beta[c0];
    float2 xi = *(const float2*)&xin[ib + c0];
    float bn0 = (acc0 - mn.x) * rsqrtf(vr.x + BN_EPS) * gm.x + bt.x;
    float bn1 = (acc1 - mn.y) * rsqrtf(vr.y + BN_EPS) * gm.y + bt.y;
    float o0 = fmaxf(xi.x + bn0, 0.f);
    float o1 = fmaxf(xi.y + bn1, 0.f);
    *(float2*)&xout[ib + c0] = make_float2(o0, o1);
    ushort_t h0 = f2bf(o0), h1 = f2bf(o1);
    ushort_t l0 = f2bf(o0 - bf2f(h0)), l1 = f2bf(o1 - bf2f(h1));
    *(uint_t*)(A2out + (size_t)i * 1024 + c0)       = (uint_t)h0 | ((uint_t)h1 << 16);
    *(uint_t*)(A2out + (size_t)i * 1024 + 512 + c0) = (uint_t)l0 | ((uint_t)l1 << 16);
}

// ---------------- GCN aggregation (bf16 in, hi/lo split out, lda 512) ----------------
__global__ __launch_bounds__(128) void k_gcn_aggr(
    const ushort_t* __restrict__ h, const float* __restrict__ dinv,
    const float* __restrict__ bias,
    const int* __restrict__ offs, const int* __restrict__ eid,
    const int* __restrict__ srcv, ushort_t* __restrict__ A2out)
{
    int i = blockIdx.x;
    int t = threadIdx.x;
    int c0 = 2 * t;
    float acc0 = 0.f, acc1 = 0.f;
    int e0 = offs[i], e1 = offs[i + 1];
    __shared__ int sS[16];
    __shared__ float sD[16];
    for (int base = e0; base < e1; base += 16) {
        int g = min(16, e1 - base);
        __syncthreads();
        if (t < g) {
            int e = eid[base + t];
            int s = srcv[e];
            sS[t] = s;
            sD[t] = dinv[s];
        }
        __syncthreads();
        for (int j = 0; j < g; j++) {
            uint_t q = *(const uint_t*)(h + (size_t)sS[j] * HDIM + c0);
            acc0 += sD[j] * bflo(q);
            acc1 += sD[j] * bfhi(q);
        }
    }
    float di = dinv[i];
    uint_t qi = *(const uint_t*)(h + (size_t)i * HDIM + c0);
    float2 b2 = *(const float2*)&bias[c0];
    float o0 = fmaxf(di * acc0 + di * di * bflo(qi) + b2.x, 0.f);
    float o1 = fmaxf(di * acc1 + di * di * bfhi(qi) + b2.y, 0.f);
    ushort_t h0 = f2bf(o0), h1 = f2bf(o1);
    ushort_t l0 = f2bf(o0 - bf2f(h0)), l1 = f2bf(o1 - bf2f(h1));
    *(uint_t*)(A2out + (size_t)i * 512 + c0)       = (uint_t)h0 | ((uint_t)h1 << 16);
    *(uint_t*)(A2out + (size_t)i * 512 + 256 + c0) = (uint_t)l0 | ((uint_t)l1 << 16);
}

// ---------------- goal-feature rank-1 precompute ----------------
__global__ void k_goalvec(const float* __restrict__ g, const float* __restrict__ W,
                          const float* __restrict__ b, float* __restrict__ cg) {
    int c = blockIdx.x * blockDim.x + threadIdx.x;
    if (c >= DIM) return;
    float acc = b[c];
    for (int k = 0; k < DIM; k++)
        acc += g[k] * W[(size_t)(HDIM + k) * DIM + c];
    cg[c] = acc;
}

// ---------------- final dot ----------------
__global__ __launch_bounds__(256) void k_final(const float* __restrict__ hd,
                                               const float* __restrict__ w2,
                                               const float* __restrict__ b2,
                                               float* __restrict__ out) {
    int wave = threadIdx.x >> 6, lane = threadIdx.x & 63;
    int i = blockIdx.x * 4 + wave;
    if (i >= N_NODES) return;
    const float* r = hd + (size_t)i * DIM;
    float acc = 0.f;
#pragma unroll
    for (int q = 0; q < 8; q++) acc += r[lane + 64 * q] * w2[lane + 64 * q];
#pragma unroll
    for (int off = 32; off > 0; off >>= 1) acc += __shfl_down(acc, off, 64);
    if (lane == 0) out[i] = acc + b2[0];
}

// ---------------- launch ----------------
extern "C" void kernel_launch(void* const* d_in, const int* in_sizes, int n_in,
                              void* d_out, int out_size, void* d_ws, size_t ws_size,
                              hipStream_t stream) {
    (void)in_sizes; (void)n_in; (void)out_size; (void)ws_size;
    const float* x      = (const float*)d_in[0];
    const float* ea     = (const float*)d_in[1];
    const float* goal   = (const float*)d_in[2];
    const float* cgWf[2] = {(const float*)d_in[3],  (const float*)d_in[11]};
    const float* cgbf[2] = {(const float*)d_in[4],  (const float*)d_in[12]};
    const float* cgWs[2] = {(const float*)d_in[5],  (const float*)d_in[13]};
    const float* cgbs[2] = {(const float*)d_in[6],  (const float*)d_in[14]};
    const float* cggm[2] = {(const float*)d_in[7],  (const float*)d_in[15]};
    const float* cgbt[2] = {(const float*)d_in[8],  (const float*)d_in[16]};
    const float* cgmn[2] = {(const float*)d_in[9],  (const float*)d_in[17]};
    const float* cgvr[2] = {(const float*)d_in[10], (const float*)d_in[18]};
    const float* gcn3_W = (const float*)d_in[19];
    const float* gcn3_b = (const float*)d_in[20];
    const float* gcn4_W = (const float*)d_in[21];
    const float* gcn4_b = (const float*)d_in[22];
    const float* d1_W   = (const float*)d_in[23];
    const float* d1_b   = (const float*)d_in[24];
    const float* d2_W   = (const float*)d_in[25];
    const float* d2_b   = (const float*)d_in[26];
    const int*   eidx   = (const int*)d_in[27];
    const int*   srcv   = eidx;
    const int*   dstv   = eidx + N_EDGES;
    float* outp = (float*)d_out;

    // ---- workspace layout (~110 MB) ----
    float*    Pbuf = (float*)d_ws;                                  // 10000*1024 f32
    ushort_t* Qbuf = (ushort_t*)(Pbuf + (size_t)N_NODES * 1024);    // 10000*1024 bf16
    float*    xB   = (float*)(Qbuf + (size_t)N_NODES * 1024);       // 10000*512 f32
    ushort_t* A2   = (ushort_t*)(xB + (size_t)N_NODES * DIM);       // 10112*1024 bf16
    ushort_t* W2t  = A2 + (size_t)MPAD * 1024;                      // 2048*1536 bf16
    float*    cgv  = (float*)(W2t + (size_t)2048 * 1536);           // 512
    int* offs   = (int*)(cgv + DIM);            // N+1
    int* cursor = offs + (N_NODES + 1);         // N
    int* eidArr = cursor + N_NODES;             // E
    float* dinv = (float*)(eidArr + N_EDGES);   // N
    uint_t* WEP = (uint_t*)(dinv + N_NODES);    // 4*4096 u32
    uint_t* WEPf[2] = {WEP, WEP + 8192};
    uint_t* WEPs[2] = {WEP + 4096, WEP + 12288};
    // tail-phase aliases
    ushort_t* h3 = (ushort_t*)Pbuf;             // N x 256 bf16
    ushort_t* h4 = h3 + (size_t)N_NODES * HDIM; // N x 256 bf16
    float*    hd = (float*)Qbuf;                // N x 512 f32

    // ---- CSR build + weight prep ----
    hipMemsetAsync(offs, 0, (N_NODES + 1) * sizeof(int), stream);
    hipMemsetAsync(cursor, 0, N_NODES * sizeof(int), stream);
    k_hist<<<(N_EDGES + 255) / 256, 256, 0, stream>>>(dstv, offs);
    k_scan<<<1, 1024, 0, stream>>>(offs, dinv);
    k_scatter<<<(N_EDGES + 255) / 256, 256, 0, stream>>>(dstv, offs, cursor, eidArr);
    k_prep_wep<<<16, 256, 0, stream>>>(cgWf[0] + 1024 * 512, cgWs[0] + 1024 * 512, WEPf[0], WEPs[0]);
    k_prep_wep<<<16, 256, 0, stream>>>(cgWf[1] + 1024 * 512, cgWs[1] + 1024 * 512, WEPf[1], WEPs[1]);

    // ---- CG layer 1 ----
    k_cvtA<<<(N_NODES * 512 + 255) / 256, 256, 0, stream>>>(x, N_NODES * 512, 9, A2);
    k_cvtW_cg<<<dim3(6, 2048), 256, 0, stream>>>(cgWf[0], cgWs[0], W2t);
    k_gemm3<<<dim3(79, 16), 256, 0, stream>>>(A2, 1024, 512, N_NODES, W2t,
                                              Pbuf, Qbuf, nullptr, 1, 0);
    k_cg_aggr<<<N_NODES, 256, 0, stream>>>(x, Pbuf, Qbuf, WEPf[0], WEPs[0],
                                           cgbf[0], cgbs[0],
                                           cggm[0], cgbt[0], cgmn[0], cgvr[0],
                                           offs, eidArr, srcv, ea, xB, A2);
    // ---- CG layer 2 ----
    k_cvtW_cg<<<dim3(6, 2048), 256, 0, stream>>>(cgWf[1], cgWs[1], W2t);
    k_gemm3<<<dim3(79, 16), 256, 0, stream>>>(A2, 1024, 512, N_NODES, W2t,
                                              Pbuf, Qbuf, nullptr, 1, 0);
    k_cg_aggr<<<N_NODES, 256, 0, stream>>>(xB, Pbuf, Qbuf, WEPf[1], WEPs[1],
                                           cgbf[1], cgbs[1],
                                           cggm[1], cgbt[1], cgmn[1], cgvr[1],
                                           offs, eidArr, srcv, ea, xB, A2);

    // ---- GCN 3: 512 -> 256 ----
    k_cvtW_plain<<<dim3(6, 256), 256, 0, stream>>>(gcn3_W, HDIM, 9, W2t);
    k_gemm3<<<dim3(79, 2), 256, 0, stream>>>(A2, 1024, 512, N_NODES, W2t,
                                             nullptr, h3, nullptr, 3, HDIM);
    k_gcn_aggr<<<N_NODES, 128, 0, stream>>>(h3, dinv, gcn3_b, offs, eidArr, srcv, A2);

    // ---- GCN 4: 256 -> 256 ----
    k_cvtW_plain<<<dim3(3, 256), 256, 0, stream>>>(gcn4_W, HDIM, 8, W2t);
    k_gemm3<<<dim3(79, 2), 256, 0, stream>>>(A2, 512, 256, N_NODES, W2t,
                                             nullptr, h4, nullptr, 3, HDIM);
    k_gcn_aggr<<<N_NODES, 128, 0, stream>>>(h4, dinv, gcn4_b, offs, eidArr, srcv, A2);

    // ---- dense head ----
    k_goalvec<<<2, 256, 0, stream>>>(goal, d1_W, d1_b, cgv);
    k_cvtW_plain<<<dim3(3, 512), 256, 0, stream>>>(d1_W, DIM, 8, W2t);
    k_gemm3<<<dim3(79, 4), 256, 0, stream>>>(A2, 512, 256, N_NODES, W2t,
                                             hd, nullptr, cgv, 2, DIM);
    k_final<<<(N_NODES + 3) / 4, 256, 0, stream>>>(hd, d2_W, d2_b, outp);
}

// Round 5
// 833.317 us; speedup vs baseline: 1.9189x; 1.0572x over previous
//
#include <hip/hip_runtime.h>

#define N_NODES 10000
#define N_EDGES 160000
#define DIM 512
#define HDIM 256
#define EDIM 16
#define BN_EPS 1e-5f

typedef unsigned short ushort_t;
typedef unsigned int uint_t;
typedef __attribute__((ext_vector_type(8))) short bf16x8;
typedef __attribute__((ext_vector_type(4))) float f32x4;
typedef __attribute__((ext_vector_type(2))) _Float16 half2_t;

// ---------------- helpers ----------------
__device__ __forceinline__ ushort_t f2bf(float x) {
    uint_t u = __float_as_uint(x);
    uint_t r = (u + 0x7FFF + ((u >> 16) & 1)) >> 16;  // RNE
    return (ushort_t)r;
}
__device__ __forceinline__ float bf2f(ushort_t h) {
    return __uint_as_float(((uint_t)h) << 16);
}
__device__ __forceinline__ float bflo(uint_t u) {
    return __uint_as_float(u << 16);
}
__device__ __forceinline__ float bfhi(uint_t u) {
    return __uint_as_float(u & 0xffff0000u);
}
__device__ __forceinline__ void gld16(const void* g, void* l) {
    __builtin_amdgcn_global_load_lds(
        (const __attribute__((address_space(1))) unsigned int*)g,
        (__attribute__((address_space(3))) unsigned int*)l, 16, 0, 0);
}
__device__ __forceinline__ half2_t u2h(uint_t u) {
    return __builtin_bit_cast(half2_t, u);
}
__device__ __forceinline__ uint_t pk_f16(float a, float b) {
    return __builtin_bit_cast(uint_t, __builtin_amdgcn_cvt_pkrtz(a, b));
}

// ---------------- CSR build ----------------
__global__ void k_hist(const int* __restrict__ dst, int* __restrict__ cnt) {
    int e = blockIdx.x * blockDim.x + threadIdx.x;
    if (e < N_EDGES) atomicAdd(&cnt[dst[e]], 1);
}

// shfl-based scan: counts -> exclusive prefix; writes dinv
__global__ __launch_bounds__(1024) void k_scan(int* __restrict__ offs, float* __restrict__ dinv) {
    __shared__ int wsum[16];
    __shared__ int carryS;
    int t = threadIdx.x, lane = t & 63, wv = t >> 6;
    if (t == 0) carryS = 0;
    __syncthreads();
    for (int base = 0; base < N_NODES; base += 1024) {
        int idx = base + t;
        int v = (idx < N_NODES) ? offs[idx] : 0;
        if (idx < N_NODES) dinv[idx] = rsqrtf((float)v + 1.0f);
        int s = v;
#pragma unroll
        for (int off = 1; off < 64; off <<= 1) {
            int u = __shfl_up(s, off, 64);
            if (lane >= off) s += u;
        }
        if (lane == 63) wsum[wv] = s;
        __syncthreads();
        int carry = carryS;
        if (wv == 0) {
            int w = (lane < 16) ? wsum[lane] : 0;
#pragma unroll
            for (int off = 1; off < 16; off <<= 1) {
                int u = __shfl_up(w, off, 64);
                if (lane >= off) w += u;
            }
            if (lane < 16) wsum[lane] = w;
        }
        __syncthreads();
        int wbase = (wv == 0) ? 0 : wsum[wv - 1];
        if (idx < N_NODES) offs[idx] = carry + wbase + s - v;
        int total = wsum[15];
        __syncthreads();
        if (t == 0) carryS = carry + total;
        __syncthreads();
    }
    if (t == 0) offs[N_NODES] = carryS;
}

// scatter edges to CSR order; also materialize src, dinv[src], packed-f16 ea per slot
__global__ void k_scatter(const int* __restrict__ srcv, const int* __restrict__ dstv,
                          const float* __restrict__ ea,
                          const int* __restrict__ offs, const float* __restrict__ dinv,
                          int* __restrict__ cursor,
                          int* __restrict__ srcArr, float* __restrict__ dinvArr,
                          uint_t* __restrict__ eaP) {
    int e = blockIdx.x * blockDim.x + threadIdx.x;
    if (e >= N_EDGES) return;
    int d = dstv[e];
    int p = offs[d] + atomicAdd(&cursor[d], 1);
    int s = srcv[e];
    srcArr[p] = s;
    dinvArr[p] = dinv[s];
    const float* er = ea + (size_t)e * EDIM;
    uint_t pk[8];
#pragma unroll
    for (int k2 = 0; k2 < 8; k2++) pk[k2] = pk_f16(er[2 * k2], er[2 * k2 + 1]);
    uint_t* q = eaP + (size_t)p * 8;
    *(uint4*)q = *(uint4*)&pk[0];
    *(uint4*)(q + 4) = *(uint4*)&pk[4];
}

// ---------------- mega prep: all weight conversions + cvtA + goalvec + wep ----------------
#define MP_CG0   12288              // 6*2048 (layer 0)
#define MP_CG1   24576              // + 6*2048 (layer 1)
#define MP_G3    26112              // + 6*256
#define MP_G4    26880              // + 3*256
#define MP_D1    28416              // + 3*512
#define MP_WEP   28448              // + 32
#define MP_GV    28456              // + 8
#define MP_END   48456              // + 20000 (cvtA)

__global__ __launch_bounds__(256) void k_megaprep(
    const float* __restrict__ x, const float* __restrict__ goal,
    const float* __restrict__ Wf0, const float* __restrict__ Ws0,
    const float* __restrict__ Wf1, const float* __restrict__ Ws1,
    const float* __restrict__ g3W, const float* __restrict__ g4W,
    const float* __restrict__ d1W, const float* __restrict__ d1b,
    ushort_t* __restrict__ A2,
    ushort_t* __restrict__ W2cg0, ushort_t* __restrict__ W2cg1,
    ushort_t* __restrict__ W2g3, ushort_t* __restrict__ W2g4,
    ushort_t* __restrict__ W2d1,
    uint_t* __restrict__ WEP, float* __restrict__ cgv)
{
    int b = blockIdx.x, t = threadIdx.x;
    if (b < MP_CG1) {
        // CG weights -> [2048 cols][1536 k], col groups [Pf|Ps|Qf|Qs]
        const float *Wf, *Ws; ushort_t* out; int bb;
        if (b < MP_CG0) { bb = b; Wf = Wf0; Ws = Ws0; out = W2cg0; }
        else            { bb = b - MP_CG0; Wf = Wf1; Ws = Ws1; out = W2cg1; }
        int k = (bb % 6) * 256 + t;
        int c2 = bb / 6;
        int part = k >> 9, kk = k & 511;
        int g = c2 >> 9, c = c2 & 511;
        const float* W = (g & 1) ? Ws : Wf;
        int roff = (g & 2) ? 512 : 0;
        float v = W[(size_t)(roff + kk) * 512 + c];
        ushort_t hi = f2bf(v);
        out[(size_t)c2 * 1536 + k] = (part == 2) ? f2bf(v - bf2f(hi)) : hi;
    } else if (b < MP_G3) {
        int bb = b - MP_CG1;           // 0..1535
        int k = (bb % 6) * 256 + t;    // 0..1535, KH=512
        int c = bb / 6;                // 0..255
        int part = k >> 9, kk = k & 511;
        float v = g3W[(size_t)kk * 256 + c];
        ushort_t hi = f2bf(v);
        W2g3[(size_t)c * 1536 + k] = (part == 2) ? f2bf(v - bf2f(hi)) : hi;
    } else if (b < MP_G4) {
        int bb = b - MP_G3;            // 0..767
        int k = (bb % 3) * 256 + t;    // 0..767, KH=256
        int c = bb / 3;                // 0..255
        int part = k >> 8, kk = k & 255;
        float v = g4W[(size_t)kk * 256 + c];
        ushort_t hi = f2bf(v);
        W2g4[(size_t)c * 768 + k] = (part == 2) ? f2bf(v - bf2f(hi)) : hi;
    } else if (b < MP_D1) {
        int bb = b - MP_G4;            // 0..1535
        int k = (bb % 3) * 256 + t;    // 0..767, KH=256
        int c = bb / 3;                // 0..511
        int part = k >> 8, kk = k & 255;
        float v = d1W[(size_t)kk * 512 + c];
        ushort_t hi = f2bf(v);
        W2d1[(size_t)c * 768 + k] = (part == 2) ? f2bf(v - bf2f(hi)) : hi;
    } else if (b < MP_WEP) {
        int bb = b - MP_D1;            // 0..31
        int layer = bb >> 4, blk = bb & 15;
        int idx = blk * 256 + t;       // 0..4095
        int c = idx >> 3, k2 = idx & 7;
        const float* Wf = (layer ? Wf1 : Wf0) + 1024 * 512;
        const float* Ws = (layer ? Ws1 : Ws0) + 1024 * 512;
        uint_t* WEPf = WEP + layer * 8192;
        uint_t* WEPs = WEPf + 4096;
        WEPf[c * 8 + k2] = pk_f16(Wf[(2 * k2) * 512 + c], Wf[(2 * k2 + 1) * 512 + c]);
        WEPs[c * 8 + k2] = pk_f16(Ws[(2 * k2) * 512 + c], Ws[(2 * k2 + 1) * 512 + c]);
    } else if (b < MP_GV) {
        // goalvec: cg[c] = d1b[c] + sum_k goal[k]*d1W[(256+k)*512+c]
        __shared__ float red[256];
        int bb = b - MP_WEP;           // 0..7
        int c = bb * 64 + (t & 63);
        int slice = t >> 6;            // 0..3
        float acc = 0.f;
        for (int i = 0; i < 128; i++) {
            int k = slice * 128 + i;
            acc += goal[k] * d1W[(size_t)(256 + k) * 512 + c];
        }
        red[t] = acc;
        __syncthreads();
        if (t < 128) red[t] += red[t + 128];
        __syncthreads();
        if (t < 64) cgv[c] = red[t] + red[t + 64] + d1b[c];
    } else {
        // cvtA for input x: [10000 x 512] f32 -> A2 [10000 x 1024] hi|lo
        int idx = (b - MP_GV) * 256 + t;
        if (idx < N_NODES * 512) {
            int m = idx >> 9, k = idx & 511;
            float v = x[idx];
            ushort_t hi = f2bf(v);
            ushort_t lo = f2bf(v - bf2f(hi));
            size_t rb = (size_t)m * 1024;
            A2[rb + k] = hi;
            A2[rb + 512 + k] = lo;
        }
    }
}

// ---------------- bf16 MFMA GEMM (split 3-term via K concatenation) ----------------
// mode 1: CG (cols<1024 -> outF f32 ld 1024; cols>=1024 -> outQ interleaved bf16 ld 1024)
// mode 2: outF = relu(v + bias[col]) f32, ldc
// mode 3: outQ = bf16(v), ldc
__global__ __launch_bounds__(256) void k_gemm3(
    const ushort_t* __restrict__ A2, int lda, int KH, int M,
    const ushort_t* __restrict__ W2t,
    float* __restrict__ outF, ushort_t* __restrict__ outQ,
    const float* __restrict__ bias, int mode, int ldc)
{
    __shared__ ushort_t As[128 * 32];
    __shared__ ushort_t Bs[128 * 32];
    const int Ktot = 3 * KH;
    int tid = threadIdx.x;
    int lane = tid & 63, w = tid >> 6;
    int wm = w & 1, wn = w >> 1;
    int lrow = lane & 15, quad = lane >> 4;
    int row0 = blockIdx.x * 128, col0 = blockIdx.y * 128;

    f32x4 acc[4][4] = {};

    int s0 = tid, s1 = 256 + tid;
    int r0 = s0 >> 2, kq0 = (s0 & 3) ^ ((r0 >> 1) & 3);
    int r1 = s1 >> 2, kq1 = (s1 & 3) ^ ((r1 >> 1) & 3);
    int gr0 = row0 + r0; if (gr0 >= M) gr0 = M - 1;   // clamp (A2 has no pad rows)
    int gr1 = row0 + r1; if (gr1 >= M) gr1 = M - 1;
    const ushort_t* Ar0 = A2 + (size_t)gr0 * lda + kq0 * 8;
    const ushort_t* Ar1 = A2 + (size_t)gr1 * lda + kq1 * 8;
    const ushort_t* Br0 = W2t + (size_t)(col0 + r0) * Ktot + kq0 * 8;
    const ushort_t* Br1 = W2t + (size_t)(col0 + r1) * Ktot + kq1 * 8;
    ushort_t* Al0 = As + s0 * 8; ushort_t* Al1 = As + s1 * 8;
    ushort_t* Bl0 = Bs + s0 * 8; ushort_t* Bl1 = Bs + s1 * 8;

    const ushort_t* afp[4];
    const ushort_t* bfp[4];
#pragma unroll
    for (int mt = 0; mt < 4; mt++) {
        int r = wm * 64 + mt * 16 + lrow;
        afp[mt] = As + r * 32 + ((quad ^ ((r >> 1) & 3)) * 8);
        int c = wn * 64 + mt * 16 + lrow;
        bfp[mt] = Bs + c * 32 + ((quad ^ ((c >> 1) & 3)) * 8);
    }

    for (int k0 = 0; k0 < Ktot; k0 += 32) {
        int ak = (k0 < 2 * KH) ? k0 : k0 - 2 * KH;  // 3rd block re-reads hi
        __syncthreads();
        gld16(Ar0 + ak, Al0);
        gld16(Ar1 + ak, Al1);
        gld16(Br0 + k0, Bl0);
        gld16(Br1 + k0, Bl1);
        __syncthreads();
        bf16x8 af[4], bff[4];
#pragma unroll
        for (int i = 0; i < 4; i++) {
            af[i]  = *(const bf16x8*)afp[i];
            bff[i] = *(const bf16x8*)bfp[i];
        }
#pragma unroll
        for (int mt = 0; mt < 4; mt++)
#pragma unroll
            for (int nt = 0; nt < 4; nt++)
                acc[mt][nt] = __builtin_amdgcn_mfma_f32_16x16x32_bf16(
                    af[mt], bff[nt], acc[mt][nt], 0, 0, 0);
    }

#pragma unroll
    for (int mt = 0; mt < 4; mt++) {
#pragma unroll
        for (int nt = 0; nt < 4; nt++) {
            int gcol = col0 + wn * 64 + nt * 16 + lrow;
#pragma unroll
            for (int r = 0; r < 4; r++) {
                int grow = row0 + wm * 64 + mt * 16 + quad * 4 + r;
                if (grow >= M) continue;
                float v = acc[mt][nt][r];
                if (mode == 1) {
                    if (gcol < 1024) {
                        outF[(size_t)grow * 1024 + gcol] = v;
                    } else {
                        int c = gcol - 1024;
                        int grp = c >> 9, cc = c & 511;
                        int pos = (cc >> 1) * 4 + grp * 2 + (cc & 1);
                        outQ[(size_t)grow * 1024 + pos] = f2bf(v);
                    }
                } else if (mode == 2) {
                    outF[(size_t)grow * ldc + gcol] = fmaxf(v + bias[gcol], 0.f);
                } else {  // mode 3
                    outQ[(size_t)grow * ldc + gcol] = f2bf(v);
                }
            }
        }
    }
}

// ---------------- CGConv aggregation + BN + residual + ReLU ----------------
// P [N x 1024] f32 = [Pf|Ps]; Qi [N x 1024] bf16 interleaved [qf0,qf1,qs0,qs1,...]
// CSR-ordered srcArr / packed-f16 eaP; depth-2 prefetch of q gathers.
__global__ __launch_bounds__(256) void k_cg_aggr(
    const float* __restrict__ xin, const float* __restrict__ P,
    const ushort_t* __restrict__ Qi,
    const uint_t* __restrict__ WEPf, const uint_t* __restrict__ WEPs,
    const float* __restrict__ bfv, const float* __restrict__ bsv,
    const float* __restrict__ gamma, const float* __restrict__ beta,
    const float* __restrict__ mean, const float* __restrict__ var,
    const int* __restrict__ offs, const int* __restrict__ srcArr,
    const uint_t* __restrict__ eaP,
    float* __restrict__ xout, ushort_t* __restrict__ A2out)
{
    int i = blockIdx.x;
    int t = threadIdx.x;
    int c0 = 2 * t;
    uint_t wfp[2][8], wsp[2][8];
    {
        const uint_t* pf8 = WEPf + c0 * 8;
        const uint_t* ps8 = WEPs + c0 * 8;
        *(uint4*)&wfp[0][0] = *(const uint4*)(pf8 + 0);
        *(uint4*)&wfp[0][4] = *(const uint4*)(pf8 + 4);
        *(uint4*)&wfp[1][0] = *(const uint4*)(pf8 + 8);
        *(uint4*)&wfp[1][4] = *(const uint4*)(pf8 + 12);
        *(uint4*)&wsp[0][0] = *(const uint4*)(ps8 + 0);
        *(uint4*)&wsp[0][4] = *(const uint4*)(ps8 + 4);
        *(uint4*)&wsp[1][0] = *(const uint4*)(ps8 + 8);
        *(uint4*)&wsp[1][4] = *(const uint4*)(ps8 + 12);
    }
    float2 pf = *(const float2*)&P[(size_t)i * 1024 + c0];
    float2 ps = *(const float2*)&P[(size_t)i * 1024 + 512 + c0];
    float2 bf2 = *(const float2*)&bfv[c0];
    float2 bs2 = *(const float2*)&bsv[c0];
    pf.x += bf2.x; pf.y += bf2.y;
    ps.x += bs2.x; ps.y += bs2.y;
    float acc0 = 0.f, acc1 = 0.f;
    int e0 = offs[i], e1 = offs[i + 1];
    __shared__ uint_t sEaP[16][8];
    __shared__ int sSrc[18];
    const ushort_t* Qbase = Qi + 4 * t;
    for (int base = e0; base < e1; base += 16) {
        int g = min(16, e1 - base);
        __syncthreads();
        if (t < 18) {
            int s = 0;
            if (t < g) s = srcArr[base + t];
            sSrc[t] = s;
        } else if (t >= 32 && t < 160) {
            int tt = t - 32;
            int j = tt >> 3, k2 = tt & 7;
            if (j < g) sEaP[j][k2] = eaP[(size_t)(base + j) * 8 + k2];
        }
        __syncthreads();
        uint2 q0 = *(const uint2*)(Qbase + ((size_t)sSrc[0] << 10));
        uint2 q1 = *(const uint2*)(Qbase + ((size_t)sSrc[1] << 10));
        for (int j = 0; j < g; j++) {
            uint2 qn = *(const uint2*)(Qbase + ((size_t)sSrc[j + 2] << 10));
            uint4 eA = *(const uint4*)&sEaP[j][0];
            uint4 eB = *(const uint4*)&sEaP[j][4];
            float gf0 = pf.x + bflo(q0.x), gf1 = pf.y + bfhi(q0.x);
            float gs0 = ps.x + bflo(q0.y), gs1 = ps.y + bfhi(q0.y);
            uint_t ek[8] = {eA.x, eA.y, eA.z, eA.w, eB.x, eB.y, eB.z, eB.w};
#pragma unroll
            for (int k = 0; k < 8; k++) {
                half2_t e2 = u2h(ek[k]);
                gf0 = __builtin_amdgcn_fdot2(e2, u2h(wfp[0][k]), gf0, false);
                gf1 = __builtin_amdgcn_fdot2(e2, u2h(wfp[1][k]), gf1, false);
                gs0 = __builtin_amdgcn_fdot2(e2, u2h(wsp[0][k]), gs0, false);
                gs1 = __builtin_amdgcn_fdot2(e2, u2h(wsp[1][k]), gs1, false);
            }
            float sg0 = __builtin_amdgcn_rcpf(1.f + __expf(-gf0));
            float sg1 = __builtin_amdgcn_rcpf(1.f + __expf(-gf1));
            float sp0 = fmaxf(gs0, 0.f) + __logf(1.f + __expf(-fabsf(gs0)));
            float sp1 = fmaxf(gs1, 0.f) + __logf(1.f + __expf(-fabsf(gs1)));
            acc0 += sg0 * sp0;
            acc1 += sg1 * sp1;
            q0 = q1; q1 = qn;
        }
    }
    size_t ib = (size_t)i * DIM;
    float2 mn = *(const float2*)&mean[c0];
    float2 vr = *(const float2*)&var[c0];
    float2 gm = *(const float2*)&gamma[c0];
    float2 bt = *(const float2*)&beta[c0];
    float2 xi = *(const float2*)&xin[ib + c0];
    float bn0 = (acc0 - mn.x) * rsqrtf(vr.x + BN_EPS) * gm.x + bt.x;
    float bn1 = (acc1 - mn.y) * rsqrtf(vr.y + BN_EPS) * gm.y + bt.y;
    float o0 = fmaxf(xi.x + bn0, 0.f);
    float o1 = fmaxf(xi.y + bn1, 0.f);
    *(float2*)&xout[ib + c0] = make_float2(o0, o1);
    ushort_t h0 = f2bf(o0), h1 = f2bf(o1);
    ushort_t l0 = f2bf(o0 - bf2f(h0)), l1 = f2bf(o1 - bf2f(h1));
    *(uint_t*)(A2out + (size_t)i * 1024 + c0)       = (uint_t)h0 | ((uint_t)h1 << 16);
    *(uint_t*)(A2out + (size_t)i * 1024 + 512 + c0) = (uint_t)l0 | ((uint_t)l1 << 16);
}

// ---------------- GCN aggregation (bf16 in, hi/lo split out, lda 512) ----------------
__global__ __launch_bounds__(128) void k_gcn_aggr(
    const ushort_t* __restrict__ h, const float* __restrict__ dinv,
    const float* __restrict__ bias,
    const int* __restrict__ offs, const int* __restrict__ srcArr,
    const float* __restrict__ dinvArr, ushort_t* __restrict__ A2out)
{
    int i = blockIdx.x;
    int t = threadIdx.x;
    int c0 = 2 * t;
    float acc0 = 0.f, acc1 = 0.f;
    int e0 = offs[i], e1 = offs[i + 1];
    __shared__ int sS[20];
    __shared__ float sD[20];
    for (int base = e0; base < e1; base += 16) {
        int g = min(16, e1 - base);
        __syncthreads();
        if (t < 20) {
            bool ok = (t < g);
            sS[t] = ok ? srcArr[base + t] : 0;
            sD[t] = ok ? dinvArr[base + t] : 0.f;
        }
        __syncthreads();
        uint_t q0 = *(const uint_t*)(h + (size_t)sS[0] * HDIM + c0);
        uint_t q1 = *(const uint_t*)(h + (size_t)sS[1] * HDIM + c0);
        uint_t q2 = *(const uint_t*)(h + (size_t)sS[2] * HDIM + c0);
        uint_t q3 = *(const uint_t*)(h + (size_t)sS[3] * HDIM + c0);
        for (int j = 0; j < g; j++) {
            uint_t qn = *(const uint_t*)(h + (size_t)sS[j + 4] * HDIM + c0);
            acc0 += sD[j] * bflo(q0);
            acc1 += sD[j] * bfhi(q0);
            q0 = q1; q1 = q2; q2 = q3; q3 = qn;
        }
    }
    float di = dinv[i];
    uint_t qi = *(const uint_t*)(h + (size_t)i * HDIM + c0);
    float2 b2 = *(const float2*)&bias[c0];
    float o0 = fmaxf(di * acc0 + di * di * bflo(qi) + b2.x, 0.f);
    float o1 = fmaxf(di * acc1 + di * di * bfhi(qi) + b2.y, 0.f);
    ushort_t h0 = f2bf(o0), h1 = f2bf(o1);
    ushort_t l0 = f2bf(o0 - bf2f(h0)), l1 = f2bf(o1 - bf2f(h1));
    *(uint_t*)(A2out + (size_t)i * 512 + c0)       = (uint_t)h0 | ((uint_t)h1 << 16);
    *(uint_t*)(A2out + (size_t)i * 512 + 256 + c0) = (uint_t)l0 | ((uint_t)l1 << 16);
}

// ---------------- final dot ----------------
__global__ __launch_bounds__(256) void k_final(const float* __restrict__ hd,
                                               const float* __restrict__ w2,
                                               const float* __restrict__ b2,
                                               float* __restrict__ out) {
    int wave = threadIdx.x >> 6, lane = threadIdx.x & 63;
    int i = blockIdx.x * 4 + wave;
    if (i >= N_NODES) return;
    const float* r = hd + (size_t)i * DIM;
    float acc = 0.f;
#pragma unroll
    for (int q = 0; q < 8; q++) acc += r[lane + 64 * q] * w2[lane + 64 * q];
#pragma unroll
    for (int off = 32; off > 0; off >>= 1) acc += __shfl_down(acc, off, 64);
    if (lane == 0) out[i] = acc + b2[0];
}

// ---------------- launch ----------------
extern "C" void kernel_launch(void* const* d_in, const int* in_sizes, int n_in,
                              void* d_out, int out_size, void* d_ws, size_t ws_size,
                              hipStream_t stream) {
    (void)in_sizes; (void)n_in; (void)out_size; (void)ws_size;
    const float* x      = (const float*)d_in[0];
    const float* ea     = (const float*)d_in[1];
    const float* goal   = (const float*)d_in[2];
    const float* cgWf[2] = {(const float*)d_in[3],  (const float*)d_in[11]};
    const float* cgbf[2] = {(const float*)d_in[4],  (const float*)d_in[12]};
    const float* cgWs[2] = {(const float*)d_in[5],  (const float*)d_in[13]};
    const float* cgbs[2] = {(const float*)d_in[6],  (const float*)d_in[14]};
    const float* cggm[2] = {(const float*)d_in[7],  (const float*)d_in[15]};
    const float* cgbt[2] = {(const float*)d_in[8],  (const float*)d_in[16]};
    const float* cgmn[2] = {(const float*)d_in[9],  (const float*)d_in[17]};
    const float* cgvr[2] = {(const float*)d_in[10], (const float*)d_in[18]};
    const float* gcn3_W = (const float*)d_in[19];
    const float* gcn3_b = (const float*)d_in[20];
    const float* gcn4_W = (const float*)d_in[21];
    const float* gcn4_b = (const float*)d_in[22];
    const float* d1_W   = (const float*)d_in[23];
    const float* d1_b   = (const float*)d_in[24];
    const float* d2_W   = (const float*)d_in[25];
    const float* d2_b   = (const float*)d_in[26];
    const int*   eidx   = (const int*)d_in[27];
    const int*   srcv   = eidx;
    const int*   dstv   = eidx + N_EDGES;
    float* outp = (float*)d_out;

    // ---- workspace layout (123.54 MB) ----
    char* w = (char*)d_ws;
    float*    Pbuf  = (float*)w;                      w += (size_t)N_NODES * 1024 * 4;
    ushort_t* Qbuf  = (ushort_t*)w;                   w += (size_t)N_NODES * 1024 * 2;
    float*    xB    = (float*)w;                      w += (size_t)N_NODES * 512 * 4;
    ushort_t* A2    = (ushort_t*)w;                   w += (size_t)N_NODES * 1024 * 2;
    ushort_t* W2cg0 = (ushort_t*)w;                   w += (size_t)2048 * 1536 * 2;
    ushort_t* W2cg1 = (ushort_t*)w;                   w += (size_t)2048 * 1536 * 2;
    ushort_t* W2g3  = (ushort_t*)w;                   w += (size_t)256 * 1536 * 2;
    ushort_t* W2g4  = (ushort_t*)w;                   w += (size_t)256 * 768 * 2;
    ushort_t* W2d1  = (ushort_t*)w;                   w += (size_t)512 * 768 * 2;
    uint_t*   eaP   = (uint_t*)w;                     w += (size_t)N_EDGES * 8 * 4;
    uint_t*   WEP   = (uint_t*)w;                     w += 16384 * 4;
    float*    cgv   = (float*)w;                      w += 512 * 4;
    int*      srcArr  = (int*)w;                      w += N_EDGES * 4;
    float*    dinvArr = (float*)w;                    w += N_EDGES * 4;
    int*      offs    = (int*)w;                      w += (N_NODES + 1) * 4;
    int*      cursor  = (int*)w;                      w += N_NODES * 4;
    float*    dinv    = (float*)w;                    w += N_NODES * 4;
    uint_t* WEPf[2] = {WEP, WEP + 8192};
    uint_t* WEPs[2] = {WEP + 4096, WEP + 12288};
    // tail-phase aliases
    ushort_t* h3 = (ushort_t*)Pbuf;
    ushort_t* h4 = h3 + (size_t)N_NODES * HDIM;
    float*    hd = (float*)Qbuf;

    // ---- prep (independent of CSR) ----
    k_megaprep<<<MP_END, 256, 0, stream>>>(x, goal,
        cgWf[0], cgWs[0], cgWf[1], cgWs[1], gcn3_W, gcn4_W, d1_W, d1_b,
        A2, W2cg0, W2cg1, W2g3, W2g4, W2d1, WEP, cgv);

    // ---- CSR build ----
    hipMemsetAsync(offs, 0, (N_NODES + 1) * sizeof(int), stream);
    hipMemsetAsync(cursor, 0, N_NODES * sizeof(int), stream);
    k_hist<<<(N_EDGES + 255) / 256, 256, 0, stream>>>(dstv, offs);
    k_scan<<<1, 1024, 0, stream>>>(offs, dinv);
    k_scatter<<<(N_EDGES + 255) / 256, 256, 0, stream>>>(srcv, dstv, ea, offs, dinv,
                                                         cursor, srcArr, dinvArr, eaP);

    // ---- CG layer 1 ----
    k_gemm3<<<dim3(79, 16), 256, 0, stream>>>(A2, 1024, 512, N_NODES, W2cg0,
                                              Pbuf, Qbuf, nullptr, 1, 0);
    k_cg_aggr<<<N_NODES, 256, 0, stream>>>(x, Pbuf, Qbuf, WEPf[0], WEPs[0],
                                           cgbf[0], cgbs[0],
                                           cggm[0], cgbt[0], cgmn[0], cgvr[0],
                                           offs, srcArr, eaP, xB, A2);
    // ---- CG layer 2 ----
    k_gemm3<<<dim3(79, 16), 256, 0, stream>>>(A2, 1024, 512, N_NODES, W2cg1,
                                              Pbuf, Qbuf, nullptr, 1, 0);
    k_cg_aggr<<<N_NODES, 256, 0, stream>>>(xB, Pbuf, Qbuf, WEPf[1], WEPs[1],
                                           cgbf[1], cgbs[1],
                                           cggm[1], cgbt[1], cgmn[1], cgvr[1],
                                           offs, srcArr, eaP, xB, A2);

    // ---- GCN 3: 512 -> 256 ----
    k_gemm3<<<dim3(79, 2), 256, 0, stream>>>(A2, 1024, 512, N_NODES, W2g3,
                                             nullptr, h3, nullptr, 3, HDIM);
    k_gcn_aggr<<<N_NODES, 128, 0, stream>>>(h3, dinv, gcn3_b, offs, srcArr, dinvArr, A2);

    // ---- GCN 4: 256 -> 256 ----
    k_gemm3<<<dim3(79, 2), 256, 0, stream>>>(A2, 512, 256, N_NODES, W2g4,
                                             nullptr, h4, nullptr, 3, HDIM);
    k_gcn_aggr<<<N_NODES, 128, 0, stream>>>(h4, dinv, gcn4_b, offs, srcArr, dinvArr, A2);

    // ---- dense head ----
    k_gemm3<<<dim3(79, 4), 256, 0, stream>>>(A2, 512, 256, N_NODES, W2d1,
                                             hd, nullptr, cgv, 2, DIM);
    k_final<<<(N_NODES + 3) / 4, 256, 0, stream>>>(hd, d2_W, d2_b, outp);
}

// Round 6
// 671.902 us; speedup vs baseline: 2.3799x; 1.2402x over previous
//
#include <hip/hip_runtime.h>

#define N_NODES 10000
#define N_EDGES 160000
#define DIM 512
#define HDIM 256
#define EDIM 16
#define BN_EPS 1e-5f

typedef unsigned short ushort_t;
typedef unsigned int uint_t;
typedef __attribute__((ext_vector_type(8))) short bf16x8;
typedef __attribute__((ext_vector_type(4))) float f32x4;
typedef __attribute__((ext_vector_type(2))) _Float16 half2_t;

// ---------------- helpers ----------------
__device__ __forceinline__ ushort_t f2bf(float x) {
    uint_t u = __float_as_uint(x);
    uint_t r = (u + 0x7FFF + ((u >> 16) & 1)) >> 16;  // RNE
    return (ushort_t)r;
}
__device__ __forceinline__ float bf2f(ushort_t h) {
    return __uint_as_float(((uint_t)h) << 16);
}
__device__ __forceinline__ float bflo(uint_t u) {
    return __uint_as_float(u << 16);
}
__device__ __forceinline__ float bfhi(uint_t u) {
    return __uint_as_float(u & 0xffff0000u);
}
__device__ __forceinline__ void gld16(const void* g, void* l) {
    __builtin_amdgcn_global_load_lds(
        (const __attribute__((address_space(1))) unsigned int*)g,
        (__attribute__((address_space(3))) unsigned int*)l, 16, 0, 0);
}
__device__ __forceinline__ half2_t u2h(uint_t u) {
    return __builtin_bit_cast(half2_t, u);
}
__device__ __forceinline__ uint_t pk_f16(float a, float b) {
    return __builtin_bit_cast(uint_t, __builtin_amdgcn_cvt_pkrtz(a, b));
}
// XCD-aware swizzle: 8 consecutive blocks = 8 x-tiles (one per XCD), same y;
// same x stays on same XCD across all y -> A-tile fetched ~once per XCD.
__device__ __forceinline__ void swz(int lid, int gx, int gy, int& bx, int& by) {
    int per = gy * 8;
    int grp = lid / per;
    int rem = lid - grp * per;
    int gsz = min(8, gx - grp * 8);
    by = rem / gsz;
    bx = grp * 8 + (rem - by * gsz);
}

// ---------------- CSR build ----------------
__global__ void k_hist(const int* __restrict__ dst, int* __restrict__ cnt) {
    int e = blockIdx.x * blockDim.x + threadIdx.x;
    if (e < N_EDGES) atomicAdd(&cnt[dst[e]], 1);
}

__global__ __launch_bounds__(1024) void k_scan(int* __restrict__ offs, float* __restrict__ dinv) {
    __shared__ int wsum[16];
    __shared__ int carryS;
    int t = threadIdx.x, lane = t & 63, wv = t >> 6;
    if (t == 0) carryS = 0;
    __syncthreads();
    for (int base = 0; base < N_NODES; base += 1024) {
        int idx = base + t;
        int v = (idx < N_NODES) ? offs[idx] : 0;
        if (idx < N_NODES) dinv[idx] = rsqrtf((float)v + 1.0f);
        int s = v;
#pragma unroll
        for (int off = 1; off < 64; off <<= 1) {
            int u = __shfl_up(s, off, 64);
            if (lane >= off) s += u;
        }
        if (lane == 63) wsum[wv] = s;
        __syncthreads();
        int carry = carryS;
        if (wv == 0) {
            int w = (lane < 16) ? wsum[lane] : 0;
#pragma unroll
            for (int off = 1; off < 16; off <<= 1) {
                int u = __shfl_up(w, off, 64);
                if (lane >= off) w += u;
            }
            if (lane < 16) wsum[lane] = w;
        }
        __syncthreads();
        int wbase = (wv == 0) ? 0 : wsum[wv - 1];
        if (idx < N_NODES) offs[idx] = carry + wbase + s - v;
        int total = wsum[15];
        __syncthreads();
        if (t == 0) carryS = carry + total;
        __syncthreads();
    }
    if (t == 0) offs[N_NODES] = carryS;
}

__global__ void k_scatter(const int* __restrict__ srcv, const int* __restrict__ dstv,
                          const float* __restrict__ ea,
                          const int* __restrict__ offs, const float* __restrict__ dinv,
                          int* __restrict__ cursor,
                          int* __restrict__ srcArr, float* __restrict__ dinvArr,
                          uint_t* __restrict__ eaP) {
    int e = blockIdx.x * blockDim.x + threadIdx.x;
    if (e >= N_EDGES) return;
    int d = dstv[e];
    int p = offs[d] + atomicAdd(&cursor[d], 1);
    int s = srcv[e];
    srcArr[p] = s;
    dinvArr[p] = dinv[s];
    const float* er = ea + (size_t)e * EDIM;
    uint_t pk[8];
#pragma unroll
    for (int k2 = 0; k2 < 8; k2++) pk[k2] = pk_f16(er[2 * k2], er[2 * k2 + 1]);
    uint_t* q = eaP + (size_t)p * 8;
    *(uint4*)q = *(uint4*)&pk[0];
    *(uint4*)(q + 4) = *(uint4*)&pk[4];
}

// ---------------- mega prep (2-term: W stores hi only, K halved) ----------------
#define MP_CG0   8192               // 4*2048 (layer 0)
#define MP_CG1   16384              // + 4*2048 (layer 1)
#define MP_G3    17408              // + 4*256
#define MP_G4    17920              // + 2*256
#define MP_D1    18944              // + 2*512
#define MP_WEP   18976              // + 32
#define MP_GV    18984              // + 8
#define MP_END   38984              // + 20000 (cvtA)

__global__ __launch_bounds__(256) void k_megaprep(
    const float* __restrict__ x, const float* __restrict__ goal,
    const float* __restrict__ Wf0, const float* __restrict__ Ws0,
    const float* __restrict__ Wf1, const float* __restrict__ Ws1,
    const float* __restrict__ g3W, const float* __restrict__ g4W,
    const float* __restrict__ d1W, const float* __restrict__ d1b,
    ushort_t* __restrict__ A2,
    ushort_t* __restrict__ W2cg0, ushort_t* __restrict__ W2cg1,
    ushort_t* __restrict__ W2g3, ushort_t* __restrict__ W2g4,
    ushort_t* __restrict__ W2d1,
    uint_t* __restrict__ WEP, float* __restrict__ cgv)
{
    int b = blockIdx.x, t = threadIdx.x;
    if (b < MP_CG1) {
        // CG weights -> [2048 cols][1024 k] (hi|hi), col groups [Pf|Ps|Qf|Qs]
        const float *Wf, *Ws; ushort_t* out; int bb;
        if (b < MP_CG0) { bb = b; Wf = Wf0; Ws = Ws0; out = W2cg0; }
        else            { bb = b - MP_CG0; Wf = Wf1; Ws = Ws1; out = W2cg1; }
        int k = (bb & 3) * 256 + t;    // 0..1023
        int c2 = bb >> 2;              // 0..2047
        int kk = k & 511;
        int g = c2 >> 9, c = c2 & 511;
        const float* W = (g & 1) ? Ws : Wf;
        int roff = (g & 2) ? 512 : 0;
        out[(size_t)c2 * 1024 + k] = f2bf(W[(size_t)(roff + kk) * 512 + c]);
    } else if (b < MP_G3) {
        int bb = b - MP_CG1;           // 0..1023
        int k = (bb & 3) * 256 + t;    // 0..1023
        int c = bb >> 2;               // 0..255
        int kk = k & 511;
        W2g3[(size_t)c * 1024 + k] = f2bf(g3W[(size_t)kk * 256 + c]);
    } else if (b < MP_G4) {
        int bb = b - MP_G3;            // 0..511
        int k = (bb & 1) * 256 + t;    // 0..511
        int c = bb >> 1;               // 0..255
        int kk = k & 255;
        W2g4[(size_t)c * 512 + k] = f2bf(g4W[(size_t)kk * 256 + c]);
    } else if (b < MP_D1) {
        int bb = b - MP_G4;            // 0..1023
        int k = (bb & 1) * 256 + t;    // 0..511
        int c = bb >> 1;               // 0..511
        int kk = k & 255;
        W2d1[(size_t)c * 512 + k] = f2bf(d1W[(size_t)kk * 512 + c]);
    } else if (b < MP_WEP) {
        int bb = b - MP_D1;            // 0..31
        int layer = bb >> 4, blk = bb & 15;
        int idx = blk * 256 + t;       // 0..4095
        int c = idx >> 3, k2 = idx & 7;
        const float* Wf = (layer ? Wf1 : Wf0) + 1024 * 512;
        const float* Ws = (layer ? Ws1 : Ws0) + 1024 * 512;
        uint_t* WEPf = WEP + layer * 8192;
        uint_t* WEPs = WEPf + 4096;
        WEPf[c * 8 + k2] = pk_f16(Wf[(2 * k2) * 512 + c], Wf[(2 * k2 + 1) * 512 + c]);
        WEPs[c * 8 + k2] = pk_f16(Ws[(2 * k2) * 512 + c], Ws[(2 * k2 + 1) * 512 + c]);
    } else if (b < MP_GV) {
        __shared__ float red[256];
        int bb = b - MP_WEP;           // 0..7
        int c = bb * 64 + (t & 63);
        int slice = t >> 6;            // 0..3
        float acc = 0.f;
        for (int i = 0; i < 128; i++) {
            int k = slice * 128 + i;
            acc += goal[k] * d1W[(size_t)(256 + k) * 512 + c];
        }
        red[t] = acc;
        __syncthreads();
        if (t < 128) red[t] += red[t + 128];
        __syncthreads();
        if (t < 64) cgv[c] = red[t] + red[t + 64] + d1b[c];
    } else {
        // cvtA: x [10000 x 512] f32 -> A2 [10000 x 1024] hi|lo
        int idx = (b - MP_GV) * 256 + t;
        if (idx < N_NODES * 512) {
            int m = idx >> 9, k = idx & 511;
            float v = x[idx];
            ushort_t hi = f2bf(v);
            ushort_t lo = f2bf(v - bf2f(hi));
            size_t rb = (size_t)m * 1024;
            A2[rb + k] = hi;
            A2[rb + 512 + k] = lo;
        }
    }
}

// ---------------- bf16 MFMA GEMM, BM=128 (2-term: Ktot = 2*KH) ----------------
// mode 1: CG (cols<1024 -> outF f32 ld 1024; cols>=1024 -> outQ interleaved bf16)
__global__ __launch_bounds__(256) void k_gemm3(
    const ushort_t* __restrict__ A2, int lda, int KH, int M,
    const ushort_t* __restrict__ W2t,
    float* __restrict__ outF, ushort_t* __restrict__ outQ,
    const float* __restrict__ bias, int mode, int ldc, int gx, int gy)
{
    __shared__ ushort_t As[128 * 32];
    __shared__ ushort_t Bs[128 * 32];
    const int Ktot = 2 * KH;
    int tid = threadIdx.x;
    int lane = tid & 63, w = tid >> 6;
    int wm = w & 1, wn = w >> 1;
    int lrow = lane & 15, quad = lane >> 4;
    int bx, by;
    swz(blockIdx.x, gx, gy, bx, by);
    int row0 = bx * 128, col0 = by * 128;

    f32x4 acc[4][4] = {};

    int s0 = tid, s1 = 256 + tid;
    int r0 = s0 >> 2, kq0 = (s0 & 3) ^ ((r0 >> 1) & 3);
    int r1 = s1 >> 2, kq1 = (s1 & 3) ^ ((r1 >> 1) & 3);
    int gr0 = row0 + r0; if (gr0 >= M) gr0 = M - 1;
    int gr1 = row0 + r1; if (gr1 >= M) gr1 = M - 1;
    const ushort_t* Ar0 = A2 + (size_t)gr0 * lda + kq0 * 8;
    const ushort_t* Ar1 = A2 + (size_t)gr1 * lda + kq1 * 8;
    const ushort_t* Br0 = W2t + (size_t)(col0 + r0) * Ktot + kq0 * 8;
    const ushort_t* Br1 = W2t + (size_t)(col0 + r1) * Ktot + kq1 * 8;
    ushort_t* Al0 = As + s0 * 8; ushort_t* Al1 = As + s1 * 8;
    ushort_t* Bl0 = Bs + s0 * 8; ushort_t* Bl1 = Bs + s1 * 8;

    const ushort_t* afp[4];
    const ushort_t* bfp[4];
#pragma unroll
    for (int mt = 0; mt < 4; mt++) {
        int r = wm * 64 + mt * 16 + lrow;
        afp[mt] = As + r * 32 + ((quad ^ ((r >> 1) & 3)) * 8);
        int c = wn * 64 + mt * 16 + lrow;
        bfp[mt] = Bs + c * 32 + ((quad ^ ((c >> 1) & 3)) * 8);
    }

    for (int k0 = 0; k0 < Ktot; k0 += 32) {
        __syncthreads();
        gld16(Ar0 + k0, Al0);
        gld16(Ar1 + k0, Al1);
        gld16(Br0 + k0, Bl0);
        gld16(Br1 + k0, Bl1);
        __syncthreads();
        bf16x8 af[4], bff[4];
#pragma unroll
        for (int i = 0; i < 4; i++) {
            af[i]  = *(const bf16x8*)afp[i];
            bff[i] = *(const bf16x8*)bfp[i];
        }
#pragma unroll
        for (int mt = 0; mt < 4; mt++)
#pragma unroll
            for (int nt = 0; nt < 4; nt++)
                acc[mt][nt] = __builtin_amdgcn_mfma_f32_16x16x32_bf16(
                    af[mt], bff[nt], acc[mt][nt], 0, 0, 0);
    }

#pragma unroll
    for (int mt = 0; mt < 4; mt++) {
#pragma unroll
        for (int nt = 0; nt < 4; nt++) {
            int gcol = col0 + wn * 64 + nt * 16 + lrow;
#pragma unroll
            for (int r = 0; r < 4; r++) {
                int grow = row0 + wm * 64 + mt * 16 + quad * 4 + r;
                if (grow >= M) continue;
                float v = acc[mt][nt][r];
                if (mode == 1) {
                    if (gcol < 1024) {
                        outF[(size_t)grow * 1024 + gcol] = v;
                    } else {
                        int c = gcol - 1024;
                        int grp = c >> 9, cc = c & 511;
                        int pos = (cc >> 1) * 4 + grp * 2 + (cc & 1);
                        outQ[(size_t)grow * 1024 + pos] = f2bf(v);
                    }
                } else if (mode == 2) {
                    outF[(size_t)grow * ldc + gcol] = fmaxf(v + bias[gcol], 0.f);
                } else {
                    outQ[(size_t)grow * ldc + gcol] = f2bf(v);
                }
            }
        }
    }
}

// ---------------- bf16 MFMA GEMM, BM=64 (for skinny tail GEMMs) ----------------
// mode 2: outF = relu(v + bias[col]); mode 3: outQ = bf16(v)
__global__ __launch_bounds__(256) void k_gemm64(
    const ushort_t* __restrict__ A2, int lda, int KH, int M,
    const ushort_t* __restrict__ W2t,
    float* __restrict__ outF, ushort_t* __restrict__ outQ,
    const float* __restrict__ bias, int mode, int ldc, int gx, int gy)
{
    __shared__ ushort_t As[64 * 32];
    __shared__ ushort_t Bs[128 * 32];
    const int Ktot = 2 * KH;
    int tid = threadIdx.x;
    int lane = tid & 63, w = tid >> 6;
    int lrow = lane & 15, quad = lane >> 4;
    int bx, by;
    swz(blockIdx.x, gx, gy, bx, by);
    int row0 = bx * 64, col0 = by * 128;

    f32x4 acc[4][2] = {};

    int sA = tid;
    int rA = sA >> 2, kqA = (sA & 3) ^ ((rA >> 1) & 3);
    int grA = row0 + rA; if (grA >= M) grA = M - 1;
    const ushort_t* ArG = A2 + (size_t)grA * lda + kqA * 8;
    ushort_t* ArL = As + sA * 8;
    int sB0 = tid, sB1 = 256 + tid;
    int rB0 = sB0 >> 2, kqB0 = (sB0 & 3) ^ ((rB0 >> 1) & 3);
    int rB1 = sB1 >> 2, kqB1 = (sB1 & 3) ^ ((rB1 >> 1) & 3);
    const ushort_t* Br0 = W2t + (size_t)(col0 + rB0) * Ktot + kqB0 * 8;
    const ushort_t* Br1 = W2t + (size_t)(col0 + rB1) * Ktot + kqB1 * 8;
    ushort_t* Bl0 = Bs + sB0 * 8;
    ushort_t* Bl1 = Bs + sB1 * 8;

    const ushort_t* afp[4];
    const ushort_t* bfp[2];
#pragma unroll
    for (int mt = 0; mt < 4; mt++) {
        int r = mt * 16 + lrow;
        afp[mt] = As + r * 32 + ((quad ^ ((r >> 1) & 3)) * 8);
    }
#pragma unroll
    for (int nt = 0; nt < 2; nt++) {
        int c = w * 32 + nt * 16 + lrow;
        bfp[nt] = Bs + c * 32 + ((quad ^ ((c >> 1) & 3)) * 8);
    }

    for (int k0 = 0; k0 < Ktot; k0 += 32) {
        __syncthreads();
        gld16(ArG + k0, ArL);
        gld16(Br0 + k0, Bl0);
        gld16(Br1 + k0, Bl1);
        __syncthreads();
        bf16x8 af[4], bff[2];
#pragma unroll
        for (int i = 0; i < 4; i++) af[i] = *(const bf16x8*)afp[i];
#pragma unroll
        for (int i = 0; i < 2; i++) bff[i] = *(const bf16x8*)bfp[i];
#pragma unroll
        for (int mt = 0; mt < 4; mt++)
#pragma unroll
            for (int nt = 0; nt < 2; nt++)
                acc[mt][nt] = __builtin_amdgcn_mfma_f32_16x16x32_bf16(
                    af[mt], bff[nt], acc[mt][nt], 0, 0, 0);
    }

#pragma unroll
    for (int mt = 0; mt < 4; mt++) {
#pragma unroll
        for (int nt = 0; nt < 2; nt++) {
            int gcol = col0 + w * 32 + nt * 16 + lrow;
#pragma unroll
            for (int r = 0; r < 4; r++) {
                int grow = row0 + mt * 16 + quad * 4 + r;
                if (grow >= M) continue;
                float v = acc[mt][nt][r];
                if (mode == 2) outF[(size_t)grow * ldc + gcol] = fmaxf(v + bias[gcol], 0.f);
                else outQ[(size_t)grow * ldc + gcol] = f2bf(v);
            }
        }
    }
}

// ---------------- CGConv aggregation + BN + residual + ReLU ----------------
__global__ __launch_bounds__(256) void k_cg_aggr(
    const float* __restrict__ xin, const float* __restrict__ P,
    const ushort_t* __restrict__ Qi,
    const uint_t* __restrict__ WEPf, const uint_t* __restrict__ WEPs,
    const float* __restrict__ bfv, const float* __restrict__ bsv,
    const float* __restrict__ gamma, const float* __restrict__ beta,
    const float* __restrict__ mean, const float* __restrict__ var,
    const int* __restrict__ offs, const int* __restrict__ srcArr,
    const uint_t* __restrict__ eaP,
    float* __restrict__ xout, ushort_t* __restrict__ A2out)
{
    int i = blockIdx.x;
    int t = threadIdx.x;
    int c0 = 2 * t;
    uint_t wfp[2][8], wsp[2][8];
    {
        const uint_t* pf8 = WEPf + c0 * 8;
        const uint_t* ps8 = WEPs + c0 * 8;
        *(uint4*)&wfp[0][0] = *(const uint4*)(pf8 + 0);
        *(uint4*)&wfp[0][4] = *(const uint4*)(pf8 + 4);
        *(uint4*)&wfp[1][0] = *(const uint4*)(pf8 + 8);
        *(uint4*)&wfp[1][4] = *(const uint4*)(pf8 + 12);
        *(uint4*)&wsp[0][0] = *(const uint4*)(ps8 + 0);
        *(uint4*)&wsp[0][4] = *(const uint4*)(ps8 + 4);
        *(uint4*)&wsp[1][0] = *(const uint4*)(ps8 + 8);
        *(uint4*)&wsp[1][4] = *(const uint4*)(ps8 + 12);
    }
    float2 pf = *(const float2*)&P[(size_t)i * 1024 + c0];
    float2 ps = *(const float2*)&P[(size_t)i * 1024 + 512 + c0];
    float2 bf2 = *(const float2*)&bfv[c0];
    float2 bs2 = *(const float2*)&bsv[c0];
    pf.x += bf2.x; pf.y += bf2.y;
    ps.x += bs2.x; ps.y += bs2.y;
    float acc0 = 0.f, acc1 = 0.f;
    int e0 = offs[i], e1 = offs[i + 1];
    __shared__ uint_t sEaP[16][8];
    __shared__ int sSrc[18];
    const ushort_t* Qbase = Qi + 4 * t;
    for (int base = e0; base < e1; base += 16) {
        int g = min(16, e1 - base);
        __syncthreads();
        if (t < 18) {
            int s = 0;
            if (t < g) s = srcArr[base + t];
            sSrc[t] = s;
        } else if (t >= 32 && t < 160) {
            int tt = t - 32;
            int j = tt >> 3, k2 = tt & 7;
            if (j < g) sEaP[j][k2] = eaP[(size_t)(base + j) * 8 + k2];
        }
        __syncthreads();
        uint2 q0 = *(const uint2*)(Qbase + ((size_t)sSrc[0] << 10));
        uint2 q1 = *(const uint2*)(Qbase + ((size_t)sSrc[1] << 10));
        for (int j = 0; j < g; j++) {
            uint2 qn = *(const uint2*)(Qbase + ((size_t)sSrc[j + 2] << 10));
            uint4 eA = *(const uint4*)&sEaP[j][0];
            uint4 eB = *(const uint4*)&sEaP[j][4];
            float gf0 = pf.x + bflo(q0.x), gf1 = pf.y + bfhi(q0.x);
            float gs0 = ps.x + bflo(q0.y), gs1 = ps.y + bfhi(q0.y);
            uint_t ek[8] = {eA.x, eA.y, eA.z, eA.w, eB.x, eB.y, eB.z, eB.w};
#pragma unroll
            for (int k = 0; k < 8; k++) {
                half2_t e2 = u2h(ek[k]);
                gf0 = __builtin_amdgcn_fdot2(e2, u2h(wfp[0][k]), gf0, false);
                gf1 = __builtin_amdgcn_fdot2(e2, u2h(wfp[1][k]), gf1, false);
                gs0 = __builtin_amdgcn_fdot2(e2, u2h(wsp[0][k]), gs0, false);
                gs1 = __builtin_amdgcn_fdot2(e2, u2h(wsp[1][k]), gs1, false);
            }
            float sg0 = __builtin_amdgcn_rcpf(1.f + __expf(-gf0));
            float sg1 = __builtin_amdgcn_rcpf(1.f + __expf(-gf1));
            float sp0 = fmaxf(gs0, 0.f) + __logf(1.f + __expf(-fabsf(gs0)));
            float sp1 = fmaxf(gs1, 0.f) + __logf(1.f + __expf(-fabsf(gs1)));
            acc0 += sg0 * sp0;
            acc1 += sg1 * sp1;
            q0 = q1; q1 = qn;
        }
    }
    size_t ib = (size_t)i * DIM;
    float2 mn = *(const float2*)&mean[c0];
    float2 vr = *(const float2*)&var[c0];
    float2 gm = *(const float2*)&gamma[c0];
    float2 bt = *(const float2*)&beta[c0];
    float2 xi = *(const float2*)&xin[ib + c0];
    float bn0 = (acc0 - mn.x) * rsqrtf(vr.x + BN_EPS) * gm.x + bt.x;
    float bn1 = (acc1 - mn.y) * rsqrtf(vr.y + BN_EPS) * gm.y + bt.y;
    float o0 = fmaxf(xi.x + bn0, 0.f);
    float o1 = fmaxf(xi.y + bn1, 0.f);
    *(float2*)&xout[ib + c0] = make_float2(o0, o1);
    ushort_t h0 = f2bf(o0), h1 = f2bf(o1);
    ushort_t l0 = f2bf(o0 - bf2f(h0)), l1 = f2bf(o1 - bf2f(h1));
    *(uint_t*)(A2out + (size_t)i * 1024 + c0)       = (uint_t)h0 | ((uint_t)h1 << 16);
    *(uint_t*)(A2out + (size_t)i * 1024 + 512 + c0) = (uint_t)l0 | ((uint_t)l1 << 16);
}

// ---------------- GCN aggregation (bf16 in, hi/lo split out, lda 512) ----------------
__global__ __launch_bounds__(128) void k_gcn_aggr(
    const ushort_t* __restrict__ h, const float* __restrict__ dinv,
    const float* __restrict__ bias,
    const int* __restrict__ offs, const int* __restrict__ srcArr,
    const float* __restrict__ dinvArr, ushort_t* __restrict__ A2out)
{
    int i = blockIdx.x;
    int t = threadIdx.x;
    int c0 = 2 * t;
    float acc0 = 0.f, acc1 = 0.f;
    int e0 = offs[i], e1 = offs[i + 1];
    __shared__ int sS[20];
    __shared__ float sD[20];
    for (int base = e0; base < e1; base += 16) {
        int g = min(16, e1 - base);
        __syncthreads();
        if (t < 20) {
            bool ok = (t < g);
            sS[t] = ok ? srcArr[base + t] : 0;
            sD[t] = ok ? dinvArr[base + t] : 0.f;
        }
        __syncthreads();
        uint_t q0 = *(const uint_t*)(h + (size_t)sS[0] * HDIM + c0);
        uint_t q1 = *(const uint_t*)(h + (size_t)sS[1] * HDIM + c0);
        uint_t q2 = *(const uint_t*)(h + (size_t)sS[2] * HDIM + c0);
        uint_t q3 = *(const uint_t*)(h + (size_t)sS[3] * HDIM + c0);
        for (int j = 0; j < g; j++) {
            uint_t qn = *(const uint_t*)(h + (size_t)sS[j + 4] * HDIM + c0);
            acc0 += sD[j] * bflo(q0);
            acc1 += sD[j] * bfhi(q0);
            q0 = q1; q1 = q2; q2 = q3; q3 = qn;
        }
    }
    float di = dinv[i];
    uint_t qi = *(const uint_t*)(h + (size_t)i * HDIM + c0);
    float2 b2 = *(const float2*)&bias[c0];
    float o0 = fmaxf(di * acc0 + di * di * bflo(qi) + b2.x, 0.f);
    float o1 = fmaxf(di * acc1 + di * di * bfhi(qi) + b2.y, 0.f);
    ushort_t h0 = f2bf(o0), h1 = f2bf(o1);
    ushort_t l0 = f2bf(o0 - bf2f(h0)), l1 = f2bf(o1 - bf2f(h1));
    *(uint_t*)(A2out + (size_t)i * 512 + c0)       = (uint_t)h0 | ((uint_t)h1 << 16);
    *(uint_t*)(A2out + (size_t)i * 512 + 256 + c0) = (uint_t)l0 | ((uint_t)l1 << 16);
}

// ---------------- final dot ----------------
__global__ __launch_bounds__(256) void k_final(const float* __restrict__ hd,
                                               const float* __restrict__ w2,
                                               const float* __restrict__ b2,
                                               float* __restrict__ out) {
    int wave = threadIdx.x >> 6, lane = threadIdx.x & 63;
    int i = blockIdx.x * 4 + wave;
    if (i >= N_NODES) return;
    const float* r = hd + (size_t)i * DIM;
    float acc = 0.f;
#pragma unroll
    for (int q = 0; q < 8; q++) acc += r[lane + 64 * q] * w2[lane + 64 * q];
#pragma unroll
    for (int off = 32; off > 0; off >>= 1) acc += __shfl_down(acc, off, 64);
    if (lane == 0) out[i] = acc + b2[0];
}

// ---------------- launch ----------------
extern "C" void kernel_launch(void* const* d_in, const int* in_sizes, int n_in,
                              void* d_out, int out_size, void* d_ws, size_t ws_size,
                              hipStream_t stream) {
    (void)in_sizes; (void)n_in; (void)out_size; (void)ws_size;
    const float* x      = (const float*)d_in[0];
    const float* ea     = (const float*)d_in[1];
    const float* goal   = (const float*)d_in[2];
    const float* cgWf[2] = {(const float*)d_in[3],  (const float*)d_in[11]};
    const float* cgbf[2] = {(const float*)d_in[4],  (const float*)d_in[12]};
    const float* cgWs[2] = {(const float*)d_in[5],  (const float*)d_in[13]};
    const float* cgbs[2] = {(const float*)d_in[6],  (const float*)d_in[14]};
    const float* cggm[2] = {(const float*)d_in[7],  (const float*)d_in[15]};
    const float* cgbt[2] = {(const float*)d_in[8],  (const float*)d_in[16]};
    const float* cgmn[2] = {(const float*)d_in[9],  (const float*)d_in[17]};
    const float* cgvr[2] = {(const float*)d_in[10], (const float*)d_in[18]};
    const float* gcn3_W = (const float*)d_in[19];
    const float* gcn3_b = (const float*)d_in[20];
    const float* gcn4_W = (const float*)d_in[21];
    const float* gcn4_b = (const float*)d_in[22];
    const float* d1_W   = (const float*)d_in[23];
    const float* d1_b   = (const float*)d_in[24];
    const float* d2_W   = (const float*)d_in[25];
    const float* d2_b   = (const float*)d_in[26];
    const int*   eidx   = (const int*)d_in[27];
    const int*   srcv   = eidx;
    const int*   dstv   = eidx + N_EDGES;
    float* outp = (float*)d_out;

    // ---- workspace layout (~118 MB) ----
    char* w = (char*)d_ws;
    float*    Pbuf  = (float*)w;                      w += (size_t)N_NODES * 1024 * 4;
    ushort_t* Qbuf  = (ushort_t*)w;                   w += (size_t)N_NODES * 1024 * 2;
    float*    xB    = (float*)w;                      w += (size_t)N_NODES * 512 * 4;
    ushort_t* A2    = (ushort_t*)w;                   w += (size_t)N_NODES * 1024 * 2;
    ushort_t* W2cg0 = (ushort_t*)w;                   w += (size_t)2048 * 1024 * 2;
    ushort_t* W2cg1 = (ushort_t*)w;                   w += (size_t)2048 * 1024 * 2;
    ushort_t* W2g3  = (ushort_t*)w;                   w += (size_t)256 * 1024 * 2;
    ushort_t* W2g4  = (ushort_t*)w;                   w += (size_t)256 * 512 * 2;
    ushort_t* W2d1  = (ushort_t*)w;                   w += (size_t)512 * 512 * 2;
    uint_t*   eaP   = (uint_t*)w;                     w += (size_t)N_EDGES * 8 * 4;
    uint_t*   WEP   = (uint_t*)w;                     w += 16384 * 4;
    float*    cgv   = (float*)w;                      w += 512 * 4;
    int*      srcArr  = (int*)w;                      w += N_EDGES * 4;
    float*    dinvArr = (float*)w;                    w += N_EDGES * 4;
    int*      offs    = (int*)w;                      w += (N_NODES + 1) * 4;
    int*      cursor  = (int*)w;                      w += N_NODES * 4;
    float*    dinv    = (float*)w;                    w += N_NODES * 4;
    uint_t* WEPf[2] = {WEP, WEP + 8192};
    uint_t* WEPs[2] = {WEP + 4096, WEP + 12288};
    ushort_t* h3 = (ushort_t*)Pbuf;
    ushort_t* h4 = h3 + (size_t)N_NODES * HDIM;
    float*    hd = (float*)Qbuf;

    // ---- prep ----
    k_megaprep<<<MP_END, 256, 0, stream>>>(x, goal,
        cgWf[0], cgWs[0], cgWf[1], cgWs[1], gcn3_W, gcn4_W, d1_W, d1_b,
        A2, W2cg0, W2cg1, W2g3, W2g4, W2d1, WEP, cgv);

    // ---- CSR build ----
    hipMemsetAsync(offs, 0, (N_NODES + 1) * sizeof(int), stream);
    hipMemsetAsync(cursor, 0, N_NODES * sizeof(int), stream);
    k_hist<<<(N_EDGES + 255) / 256, 256, 0, stream>>>(dstv, offs);
    k_scan<<<1, 1024, 0, stream>>>(offs, dinv);
    k_scatter<<<(N_EDGES + 255) / 256, 256, 0, stream>>>(srcv, dstv, ea, offs, dinv,
                                                         cursor, srcArr, dinvArr, eaP);

    // ---- CG layer 1 ----
    k_gemm3<<<79 * 16, 256, 0, stream>>>(A2, 1024, 512, N_NODES, W2cg0,
                                         Pbuf, Qbuf, nullptr, 1, 0, 79, 16);
    k_cg_aggr<<<N_NODES, 256, 0, stream>>>(x, Pbuf, Qbuf, WEPf[0], WEPs[0],
                                           cgbf[0], cgbs[0],
                                           cggm[0], cgbt[0], cgmn[0], cgvr[0],
                                           offs, srcArr, eaP, xB, A2);
    // ---- CG layer 2 ----
    k_gemm3<<<79 * 16, 256, 0, stream>>>(A2, 1024, 512, N_NODES, W2cg1,
                                         Pbuf, Qbuf, nullptr, 1, 0, 79, 16);
    k_cg_aggr<<<N_NODES, 256, 0, stream>>>(xB, Pbuf, Qbuf, WEPf[1], WEPs[1],
                                           cgbf[1], cgbs[1],
                                           cggm[1], cgbt[1], cgmn[1], cgvr[1],
                                           offs, srcArr, eaP, xB, A2);

    // ---- GCN 3: 512 -> 256 ----
    k_gemm64<<<157 * 2, 256, 0, stream>>>(A2, 1024, 512, N_NODES, W2g3,
                                          nullptr, h3, nullptr, 3, HDIM, 157, 2);
    k_gcn_aggr<<<N_NODES, 128, 0, stream>>>(h3, dinv, gcn3_b, offs, srcArr, dinvArr, A2);

    // ---- GCN 4: 256 -> 256 ----
    k_gemm64<<<157 * 2, 256, 0, stream>>>(A2, 512, 256, N_NODES, W2g4,
                                          nullptr, h4, nullptr, 3, HDIM, 157, 2);
    k_gcn_aggr<<<N_NODES, 128, 0, stream>>>(h4, dinv, gcn4_b, offs, srcArr, dinvArr, A2);

    // ---- dense head ----
    k_gemm64<<<157 * 4, 256, 0, stream>>>(A2, 512, 256, N_NODES, W2d1,
                                          hd, nullptr, cgv, 2, DIM, 157, 4);
    k_final<<<(N_NODES + 3) / 4, 256, 0, stream>>>(hd, d2_W, d2_b, outp);
}